// Round 9
// baseline (273.101 us; speedup 1.0000x reference)
//
#include <hip/hip_runtime.h>
#include <hip/hip_bf16.h>
#include <math.h>

typedef short bf16x8 __attribute__((ext_vector_type(8)));
typedef float f32x4 __attribute__((ext_vector_type(4)));

#define MFMA16 __builtin_amdgcn_mfma_f32_16x16x32_bf16

constexpr int Zc = 8, Hc = 64, Dc = 24, Tc = 512, Bc = 128, LEN = 514;
constexpr int Nn = Bc * Tc;                // 65536
constexpr size_t FRAG_Z  = 60 * 1024;      // bytes of frags per z
constexpr size_t BIAS2_BASE = 8 * FRAG_Z;              // 491520 (8 z * 768B compact bias)
constexpr size_t PART_BASE  = BIAS2_BASE + 8 * 768;    // 497664 (+64KB partials)

// magic row permutation: tile t, tile-row i (0..15) -> actual output index
__device__ __forceinline__ int magicRow(int t, int i) {
    return 32 * (t >> 1) + 8 * (i >> 2) + 4 * (t & 1) + (i & 3);
}
__device__ __forceinline__ uint32_t rn16(float v) {  // f32 -> bf16 bits (RNE)
    uint32_t u = __builtin_bit_cast(uint32_t, v);
    return ((u + 0x7FFFu + ((u >> 16) & 1u)) >> 16) & 0xFFFFu;
}
// main-kernel pack: single HW instruction, RNE. lo = bf16(a), hi = bf16(b)
__device__ __forceinline__ uint32_t cvtpk(float a, float b) {
    uint32_t r;
    asm("v_cvt_pk_bf16_f32 %0, %1, %2" : "=v"(r) : "v"(a), "v"(b));
    return r;
}
__device__ __forceinline__ float lowf(uint32_t u)  { return __builtin_bit_cast(float, u << 16); }
__device__ __forceinline__ float highf(uint32_t u) { return __builtin_bit_cast(float, u & 0xFFFF0000u); }

// 16B store at 4B alignment (CDNA supports dword-aligned dwordx4 global access)
__device__ __forceinline__ void store4u(float* p, f32x4 v) {
    asm volatile("global_store_dwordx4 %0, %1, off" :: "v"(p), "v"(v) : "memory");
}

// async global -> LDS, 16B per lane (dest = uniform base + lane*16)
__device__ __forceinline__ void gload16(const char* g, char* l) {
    __builtin_amdgcn_global_load_lds(
        (const __attribute__((address_space(1))) void*)g,
        (__attribute__((address_space(3))) void*)l, 16, 0, 0);
}

__device__ __forceinline__ bf16x8 ldfragS(const char* s, int f, int lane) {
    return *(const bf16x8*)(s + f * 1024 + (size_t)lane * 16);  // ds_read_b128 offset:f*1024
}
__device__ __forceinline__ bf16x8 mkfrag(const uint32_t* w) {
    union { uint32_t u[4]; bf16x8 f; } u;
    u.u[0] = w[0]; u.u[1] = w[1]; u.u[2] = w[2]; u.u[3] = w[3]; return u.f;
}

// ---------------- prep: build weight fragments + compact bias pages in ws ----------------
// frag index map (per z, each frag = 64 lanes x 16B):
//  0..3  W0hi (t, ks=0, k=d pad32, col24=b0)   4..7  W0lo
//  8..15 W1hi (t*2+ks)  16..23 W1lo  24..31 W2hi  32..39 W2lo
// 40..47 W2T  48..55 W1T  56..59 W0T (natural rows d, t*2+ks)
// bias page per z: 3 sel (b1,b2,Wout) x 64 floats, idx = q*16 + t*4 + r -> vec[magicRow(t,4q+r)]
__global__ void prep_kernel(const float* __restrict__ W0, const float* __restrict__ b0,
                            const float* __restrict__ W1, const float* __restrict__ W2,
                            const float* __restrict__ b1, const float* __restrict__ b2,
                            const float* __restrict__ Wout, char* __restrict__ ws)
{
    int idx = blockIdx.x * 256 + threadIdx.x;
    const int NFRAGL = 60 * 64 * 8;  // 30720
    if (idx < NFRAGL) {
        int z = idx / (60 * 64);
        int rem = idx % (60 * 64);
        int f = rem >> 6, l = rem & 63;
        int q = l >> 4, i = l & 15;
        uint32_t bits[8];
        #pragma unroll
        for (int e = 0; e < 8; ++e) {
            int kk = q * 8 + e;      // 0..31 within K-step
            float c = 0.f; bool lo = false;
            if (f < 8) {                       // W0 (K=24 + bias col 24)
                int t = f & 3; lo = (f >= 4);
                int o = magicRow(t, i);
                if (kk < 24) c = W0[(z * 64 + o) * 24 + kk];
                else if (kk == 24) c = b0[z * 64 + o];
            } else if (f < 24) {               // W1[g,h], o=g, k=h
                int g = (f - 8) & 7; lo = (f >= 16);
                int t = g >> 1, ks = g & 1, k = ks * 32 + kk;
                int o = magicRow(t, i);
                c = W1[(z * 64 + o) * 64 + k];
            } else if (f < 40) {               // W2[g,h]
                int g = (f - 24) & 7; lo = (f >= 32);
                int t = g >> 1, ks = g & 1, k = ks * 32 + kk;
                int o = magicRow(t, i);
                c = W2[(z * 64 + o) * 64 + k];
            } else if (f < 48) {               // W2T: o=h, k=g
                int g = f - 40; int t = g >> 1, ks = g & 1, k = ks * 32 + kk;
                int o = magicRow(t, i);
                c = W2[(z * 64 + k) * 64 + o];
            } else if (f < 56) {               // W1T
                int g = f - 48; int t = g >> 1, ks = g & 1, k = ks * 32 + kk;
                int o = magicRow(t, i);
                c = W1[(z * 64 + k) * 64 + o];
            } else {                           // W0T: o=d (natural), k=h
                int g = f - 56; int t = g >> 1, ks = g & 1, k = ks * 32 + kk;
                int o = t * 16 + i;
                c = (o < 24) ? W0[(z * 64 + k) * 24 + o] : 0.f;
            }
            if (lo) {
                uint32_t hb = rn16(c);
                float hf = __builtin_bit_cast(float, hb << 16);
                bits[e] = rn16(c - hf);
            } else bits[e] = rn16(c);
        }
        uint4 w;
        w.x = bits[0] | (bits[1] << 16);
        w.y = bits[2] | (bits[3] << 16);
        w.z = bits[4] | (bits[5] << 16);
        w.w = bits[6] | (bits[7] << 16);
        uint4* dst = (uint4*)(ws + (size_t)z * FRAG_Z + (size_t)f * 1024);
        dst[l] = w;
    } else if (idx < NFRAGL + 1536) {
        int j2 = idx - NFRAGL;
        int z = j2 / 192, rem = j2 % 192, sel = rem >> 6, l = rem & 63;
        int q = l >> 4, t = (l >> 2) & 3, r = l & 3;
        const float* vec = (sel == 0) ? b1 + z * 64 : (sel == 1) ? b2 + z * 64 : Wout + z * 64;
        ((float*)(ws + BIAS2_BASE))[z * 192 + sel * 64 + l] = vec[magicRow(t, 4 * q + r)];
    }
}

// ---------------- main kernel: 512 threads, one z per block, two-stage 40KB LDS ----------------
__global__ __launch_bounds__(512, 8)
void flow_main(const float* __restrict__ x, const float* __restrict__ bout,
               const char* __restrict__ ws, float* __restrict__ out,
               float* __restrict__ partial)
{
    const int lane = threadIdx.x & 63;
    const int wv   = threadIdx.x >> 6;   // 0..7
    const int q    = lane >> 4;
    const int iN   = lane & 15;
    const int blk  = blockIdx.x;    // 0..255
    const int z    = blockIdx.y;    // 0..7
    const int rowstart = blk * 256 + wv * 32;

    __shared__ __align__(16) char smem[40 * 1024];   // stage1: frags 0..39; stage2: frags 40..59 -> bytes 0..20K

    const char* gz = ws + (size_t)z * FRAG_Z;
    const char* gbias = ws + BIAS2_BASE + (size_t)z * 768;

    // ---- stage 1: forward frags 0..39 (5 per wave), issued before input pack ----
    #pragma unroll
    for (int i = 0; i < 5; ++i) {
        int f = wv * 5 + i;
        gload16(gz + f * 1024 + lane * 16, smem + f * 1024 + lane * 16);
    }

    // ---- input frags, split hi/lo (overlaps with staging) ----
    uint32_t bhi[2][4], blo[2][4];
    #pragma unroll
    for (int rt = 0; rt < 2; ++rt) {
        int n = rowstart + rt * 16 + iN;
        int b = n >> 9, t = n & 511;
        if (q < 3) {
            const float4* xp = (const float4*)(x + (size_t)(b * LEN + t) * 8 + q * 8);
            float4 A = xp[0], B = xp[1];
            float vv[8] = {A.x, A.y, A.z, A.w, B.x, B.y, B.z, B.w};
            #pragma unroll
            for (int p = 0; p < 4; ++p) {
                uint32_t hi = cvtpk(vv[2 * p], vv[2 * p + 1]);
                bhi[rt][p] = hi;
                blo[rt][p] = cvtpk(vv[2 * p] - lowf(hi), vv[2 * p + 1] - highf(hi));
            }
        } else {   // k=24 -> 1.0 (bias slot), rest 0
            bhi[rt][0] = 0x00003F80u; bhi[rt][1] = bhi[rt][2] = bhi[rt][3] = 0;
            blo[rt][0] = blo[rt][1] = blo[rt][2] = blo[rt][3] = 0;
        }
    }
    float boutz = bout[z];

    __syncthreads();   // drains vmcnt -> forward frags visible to all waves

    float asld = 0.f;
    f32x4 acc[2][4];

    // ---------- L0: h0 = W0 * full (+bias via k=24) ----------
    {
        bf16x8 wf[4];
        #pragma unroll
        for (int t = 0; t < 4; ++t) wf[t] = ldfragS(smem, t, lane);
        #pragma unroll
        for (int rt = 0; rt < 2; ++rt) {
            bf16x8 bh = mkfrag(bhi[rt]), bl = mkfrag(blo[rt]);
            #pragma unroll
            for (int t = 0; t < 4; ++t) {
                f32x4 a = {0.f, 0.f, 0.f, 0.f};
                a = MFMA16(wf[t], bh, a, 0, 0, 0);
                a = MFMA16(wf[t], bl, a, 0, 0, 0);
                acc[rt][t] = a;
            }
        }
        #pragma unroll
        for (int t = 0; t < 4; ++t) wf[t] = ldfragS(smem, 4 + t, lane);  // W0lo
        #pragma unroll
        for (int rt = 0; rt < 2; ++rt) {
            bf16x8 bh = mkfrag(bhi[rt]);
            #pragma unroll
            for (int t = 0; t < 4; ++t)
                acc[rt][t] = MFMA16(wf[t], bh, acc[rt][t], 0, 0, 0);
        }
    }
    // leaky + split-pack a0
    uint32_t a0h[2][8], a0l[2][8];
    #pragma unroll
    for (int rt = 0; rt < 2; ++rt) {
        #pragma unroll
        for (int t = 0; t < 4; ++t)
            #pragma unroll
            for (int r = 0; r < 4; ++r) {
                float v = acc[rt][t][r];
                acc[rt][t][r] = fmaxf(v, 0.2f * v);
            }
        #pragma unroll
        for (int ks = 0; ks < 2; ++ks)
            #pragma unroll
            for (int wd = 0; wd < 4; ++wd) {
                int tt = 2 * ks + (wd >> 1), rr = (wd & 1) * 2;
                float v0 = acc[rt][tt][rr], v1 = acc[rt][tt][rr + 1];
                uint32_t hi = cvtpk(v0, v1);
                a0h[rt][ks * 4 + wd] = hi;
                a0l[rt][ks * 4 + wd] = cvtpk(v0 - lowf(hi), v1 - highf(hi));
            }
    }

    // ---------- L1 ----------
    {
        union { float4 v; f32x4 a; } bb[4];
        const float4* bp = (const float4*)(gbias + 0 * 256 + q * 64);
        #pragma unroll
        for (int t = 0; t < 4; ++t) bb[t].v = bp[t];
        bf16x8 wf[8];
        #pragma unroll
        for (int g = 0; g < 8; ++g) wf[g] = ldfragS(smem, 8 + g, lane);
        #pragma unroll
        for (int rt = 0; rt < 2; ++rt)
            #pragma unroll
            for (int t = 0; t < 4; ++t) {
                f32x4 a = bb[t].a;
                #pragma unroll
                for (int ks = 0; ks < 2; ++ks) {
                    a = MFMA16(wf[t * 2 + ks], mkfrag(&a0h[rt][ks * 4]), a, 0, 0, 0);
                    a = MFMA16(wf[t * 2 + ks], mkfrag(&a0l[rt][ks * 4]), a, 0, 0, 0);
                }
                acc[rt][t] = a;
            }
        #pragma unroll
        for (int g = 0; g < 8; ++g) wf[g] = ldfragS(smem, 16 + g, lane);  // W1lo
        #pragma unroll
        for (int rt = 0; rt < 2; ++rt)
            #pragma unroll
            for (int t = 0; t < 4; ++t) {
                f32x4 a = acc[rt][t];
                #pragma unroll
                for (int ks = 0; ks < 2; ++ks)
                    a = MFMA16(wf[t * 2 + ks], mkfrag(&a0h[rt][ks * 4]), a, 0, 0, 0);
                acc[rt][t] = a;
            }
    }
    // leaky + split-pack a1 (keep a0h for d0 signs)
    uint32_t a1h[2][8], a1l[2][8];
    #pragma unroll
    for (int rt = 0; rt < 2; ++rt) {
        #pragma unroll
        for (int t = 0; t < 4; ++t)
            #pragma unroll
            for (int r = 0; r < 4; ++r) {
                float v = acc[rt][t][r];
                acc[rt][t][r] = fmaxf(v, 0.2f * v);
            }
        #pragma unroll
        for (int ks = 0; ks < 2; ++ks)
            #pragma unroll
            for (int wd = 0; wd < 4; ++wd) {
                int tt = 2 * ks + (wd >> 1), rr = (wd & 1) * 2;
                float v0 = acc[rt][tt][rr], v1 = acc[rt][tt][rr + 1];
                uint32_t hi = cvtpk(v0, v1);
                a1h[rt][ks * 4 + wd] = hi;
                a1l[rt][ks * 4 + wd] = cvtpk(v0 - lowf(hi), v1 - highf(hi));
            }
    }

    __syncthreads();   // all waves done reading frags 0..23 -> safe to overwrite bytes 0..20K

    // ---- stage 2: backward frags 40..59 -> LDS bytes 0..20K (j = wv, wv+8, wv+16) ----
    #pragma unroll
    for (int k = 0; k < 3; ++k) {
        int jj = wv + 8 * k;
        if (jj < 20)
            gload16(gz + (40 + jj) * 1024 + lane * 16, smem + jj * 1024 + lane * 16);
    }

    // ---------- L2 (frags 24..39, untouched by stage 2) ----------
    {
        union { float4 v; f32x4 a; } bb[4];
        const float4* bp = (const float4*)(gbias + 1 * 256 + q * 64);
        #pragma unroll
        for (int t = 0; t < 4; ++t) bb[t].v = bp[t];
        bf16x8 wf[8];
        #pragma unroll
        for (int g = 0; g < 8; ++g) wf[g] = ldfragS(smem, 24 + g, lane);
        #pragma unroll
        for (int rt = 0; rt < 2; ++rt)
            #pragma unroll
            for (int t = 0; t < 4; ++t) {
                f32x4 a = bb[t].a;
                #pragma unroll
                for (int ks = 0; ks < 2; ++ks) {
                    a = MFMA16(wf[t * 2 + ks], mkfrag(&a1h[rt][ks * 4]), a, 0, 0, 0);
                    a = MFMA16(wf[t * 2 + ks], mkfrag(&a1l[rt][ks * 4]), a, 0, 0, 0);
                }
                acc[rt][t] = a;
            }
        #pragma unroll
        for (int g = 0; g < 8; ++g) wf[g] = ldfragS(smem, 32 + g, lane);  // W2lo
        #pragma unroll
        for (int rt = 0; rt < 2; ++rt)
            #pragma unroll
            for (int t = 0; t < 4; ++t) {
                f32x4 a = acc[rt][t];
                #pragma unroll
                for (int ks = 0; ks < 2; ++ks)
                    a = MFMA16(wf[t * 2 + ks], mkfrag(&a1h[rt][ks * 4]), a, 0, 0, 0);
                acc[rt][t] = a;
            }
    }

    // ---------- out + t2 = d2*Wout (t2v is exactly the reference d2∘Wout) ----------
    float wl[16];
    {
        const float4* wp = (const float4*)(gbias + 2 * 256 + q * 64);
        #pragma unroll
        for (int t = 0; t < 4; ++t) {
            float4 v = wp[t];
            wl[t * 4 + 0] = v.x; wl[t * 4 + 1] = v.y; wl[t * 4 + 2] = v.z; wl[t * 4 + 3] = v.w;
        }
    }
    float ov[2];
    uint32_t t2p[2][8];
    #pragma unroll
    for (int rt = 0; rt < 2; ++rt) {
        float o = 0.f;
        float t2v[16];
        #pragma unroll
        for (int t = 0; t < 4; ++t)
            #pragma unroll
            for (int r = 0; r < 4; ++r) {
                float h = acc[rt][t][r];
                float w = wl[t * 4 + r];
                float tv = (h > 0.f) ? w : 0.2f * w;
                t2v[t * 4 + r] = tv;
                o = fmaf(h, tv, o);     // h * (d2*w) == a2 * w
            }
        #pragma unroll
        for (int ks = 0; ks < 2; ++ks)
            #pragma unroll
            for (int wd = 0; wd < 4; ++wd) {
                int tt = 2 * ks + (wd >> 1), rr = (wd & 1) * 2;
                t2p[rt][ks * 4 + wd] = cvtpk(t2v[tt * 4 + rr], t2v[tt * 4 + rr + 1]);
            }
        o += __shfl_xor(o, 16);
        o += __shfl_xor(o, 32);
        ov[rt] = o + boutz;
    }
    if (q == 0) {
        out[(size_t)(rowstart + 0 * 16 + iN) * 8 + z] = ov[0];
        out[(size_t)(rowstart + 1 * 16 + iN) * 8 + z] = ov[1];
    }

    __syncthreads();   // drains stage-2 vmcnt -> backward frags visible

    // ---------- G1 = W2T * t2, then *d1 (W2T at LDS 0..7) ----------
    uint32_t g1p[2][8];
    {
        bf16x8 wf[8];
        #pragma unroll
        for (int g = 0; g < 8; ++g) wf[g] = ldfragS(smem, g, lane);
        #pragma unroll
        for (int rt = 0; rt < 2; ++rt)
            #pragma unroll
            for (int t = 0; t < 4; ++t) {
                f32x4 a = {0.f, 0.f, 0.f, 0.f};
                #pragma unroll
                for (int ks = 0; ks < 2; ++ks)
                    a = MFMA16(wf[t * 2 + ks], mkfrag(&t2p[rt][ks * 4]), a, 0, 0, 0);
                acc[rt][t] = a;
            }
        #pragma unroll
        for (int rt = 0; rt < 2; ++rt) {
            #pragma unroll
            for (int t = 0; t < 4; ++t)
                #pragma unroll
                for (int r = 0; r < 4; ++r) {
                    uint32_t pw = a1h[rt][(t >> 1) * 4 + (t & 1) * 2 + (r >> 1)];
                    uint32_t neg = (pw >> (15 + 16 * (r & 1))) & 1u;
                    acc[rt][t][r] *= neg ? 0.2f : 1.0f;
                }
            #pragma unroll
            for (int ks = 0; ks < 2; ++ks)
                #pragma unroll
                for (int wd = 0; wd < 4; ++wd) {
                    int tt = 2 * ks + (wd >> 1), rr = (wd & 1) * 2;
                    g1p[rt][ks * 4 + wd] = cvtpk(acc[rt][tt][rr], acc[rt][tt][rr + 1]);
                }
        }
    }
    // ---------- G0 = W1T * g1, then *d0 (W1T at LDS 8..15) ----------
    uint32_t g0p[2][8];
    {
        bf16x8 wf[8];
        #pragma unroll
        for (int g = 0; g < 8; ++g) wf[g] = ldfragS(smem, 8 + g, lane);
        #pragma unroll
        for (int rt = 0; rt < 2; ++rt)
            #pragma unroll
            for (int t = 0; t < 4; ++t) {
                f32x4 a = {0.f, 0.f, 0.f, 0.f};
                #pragma unroll
                for (int ks = 0; ks < 2; ++ks)
                    a = MFMA16(wf[t * 2 + ks], mkfrag(&g1p[rt][ks * 4]), a, 0, 0, 0);
                acc[rt][t] = a;
            }
        #pragma unroll
        for (int rt = 0; rt < 2; ++rt) {
            #pragma unroll
            for (int t = 0; t < 4; ++t)
                #pragma unroll
                for (int r = 0; r < 4; ++r) {
                    uint32_t pw = a0h[rt][(t >> 1) * 4 + (t & 1) * 2 + (r >> 1)];
                    uint32_t neg = (pw >> (15 + 16 * (r & 1))) & 1u;
                    acc[rt][t][r] *= neg ? 0.2f : 1.0f;
                }
            #pragma unroll
            for (int ks = 0; ks < 2; ++ks)
                #pragma unroll
                for (int wd = 0; wd < 4; ++wd) {
                    int tt = 2 * ks + (wd >> 1), rr = (wd & 1) * 2;
                    g0p[rt][ks * 4 + wd] = cvtpk(acc[rt][tt][rr], acc[rt][tt][rr + 1]);
                }
        }
    }
    // ---------- Jac = W0T * g0 (W0T at LDS 16..19) ----------
    f32x4 aj[2][2];
    {
        bf16x8 wf[4];
        #pragma unroll
        for (int g = 0; g < 4; ++g) wf[g] = ldfragS(smem, 16 + g, lane);
        #pragma unroll
        for (int rt = 0; rt < 2; ++rt)
            #pragma unroll
            for (int t = 0; t < 2; ++t) {
                f32x4 a = {0.f, 0.f, 0.f, 0.f};
                #pragma unroll
                for (int ks = 0; ks < 2; ++ks)
                    a = MFMA16(wf[t * 2 + ks], mkfrag(&g0p[rt][ks * 4]), a, 0, 0, 0);
                aj[rt][t] = a;
            }
    }

    // diag -> log|.| (diag d=16+z lives in tile1, reg z&3, lanes q==z>>2)
    {
        int zr = z & 3, zq = z >> 2;
        #pragma unroll
        for (int rt = 0; rt < 2; ++rt) {
            f32x4 d4 = aj[rt][1];
            float dv = (zr == 0) ? d4[0] : (zr == 1) ? d4[1] : (zr == 2) ? d4[2] : d4[3];
            float lg = __logf(fabsf(dv));
            asld += (q == zq) ? lg : 0.f;
        }
    }

    // ---------- hist_jac: direct global stores (no LDS transpose) ----------
    {
        uint32_t DW = 16 + z;
        size_t hb = 524416 + (size_t)65536 * (16 * z + (z * (z - 1)) / 2);
        #pragma unroll
        for (int rt = 0; rt < 2; ++rt) {
            int n = rowstart + rt * 16 + iN;
            float* rowp = out + hb + (size_t)n * DW;
            store4u(rowp + q * 4, aj[rt][0]);      // 16B at 4B alignment
            #pragma unroll
            for (int r = 0; r < 4; ++r)
                if (q * 4 + r < z) rowp[16 + q * 4 + r] = aj[rt][1][r];
        }
    }

    // deterministic wave-sum of log|diag|, one partial per (block, wave)
    #pragma unroll
    for (int off = 1; off < 64; off <<= 1) asld += __shfl_xor(asld, off);
    if (lane == 0) partial[(size_t)(z * 256 + blk) * 8 + wv] = asld;
}

// sld[b] = deterministic fixed-order sum of its 128 partials
__global__ void reduce_sld(const float* __restrict__ partial, float* __restrict__ sld)
{
    int b = threadIdx.x;   // 0..127
    float s = 0.f;
    #pragma unroll
    for (int z = 0; z < 8; ++z)
        #pragma unroll
        for (int k = 0; k < 2; ++k)
            #pragma unroll
            for (int w = 0; w < 8; ++w)
                s += partial[(size_t)(z * 256 + b * 2 + k) * 8 + w];
    sld[b] = s;
}

extern "C" void kernel_launch(void* const* d_in, const int* in_sizes, int n_in,
                              void* d_out, int out_size, void* d_ws, size_t ws_size,
                              hipStream_t stream) {
    const float* x    = (const float*)d_in[0];
    const float* W0   = (const float*)d_in[1];
    const float* b0   = (const float*)d_in[2];
    const float* W1   = (const float*)d_in[3];
    const float* b1   = (const float*)d_in[4];
    const float* W2   = (const float*)d_in[5];
    const float* b2   = (const float*)d_in[6];
    const float* Wout = (const float*)d_in[7];
    const float* bout = (const float*)d_in[8];

    char* ws = (char*)d_ws;
    float* out = (float*)d_out;
    float* partial = (float*)(ws + PART_BASE);

    prep_kernel<<<126, 256, 0, stream>>>(W0, b0, W1, W2, b1, b2, Wout, ws);
    flow_main<<<dim3(256, 8), 512, 0, stream>>>(x, bout, (const char*)ws, out, partial);
    reduce_sld<<<1, 128, 0, stream>>>((const float*)partial, out + (size_t)Nn * Zc);
}

// Round 10
// 60.195 us; speedup vs baseline: 4.5369x; 4.5369x over previous
//
#include <hip/hip_runtime.h>
#include <hip/hip_bf16.h>
#include <math.h>

typedef short bf16x8 __attribute__((ext_vector_type(8)));
typedef float f32x4 __attribute__((ext_vector_type(4)));

#define MFMA16 __builtin_amdgcn_mfma_f32_16x16x32_bf16

constexpr int Zc = 8, Hc = 64, Dc = 24, Tc = 512, Bc = 128, LEN = 514;
constexpr int Nn = Bc * Tc;                // 65536
constexpr size_t FRAG_Z  = 60 * 1024;      // bytes of frags per z
constexpr size_t BIAS2_BASE = 8 * FRAG_Z;              // 491520 (8 z * 768B compact bias)
constexpr size_t PART_BASE  = BIAS2_BASE + 8 * 768;    // 497664 (+64KB partials)

// magic row permutation: tile t, tile-row i (0..15) -> actual output index
__device__ __forceinline__ int magicRow(int t, int i) {
    return 32 * (t >> 1) + 8 * (i >> 2) + 4 * (t & 1) + (i & 3);
}
__device__ __forceinline__ uint32_t rn16(float v) {  // f32 -> bf16 bits (RNE)
    uint32_t u = __builtin_bit_cast(uint32_t, v);
    return ((u + 0x7FFFu + ((u >> 16) & 1u)) >> 16) & 0xFFFFu;
}
// main-kernel pack: single HW instruction, RNE. lo = bf16(a), hi = bf16(b)
__device__ __forceinline__ uint32_t cvtpk(float a, float b) {
    uint32_t r;
    asm("v_cvt_pk_bf16_f32 %0, %1, %2" : "=v"(r) : "v"(a), "v"(b));
    return r;
}
__device__ __forceinline__ float lowf(uint32_t u)  { return __builtin_bit_cast(float, u << 16); }
__device__ __forceinline__ float highf(uint32_t u) { return __builtin_bit_cast(float, u & 0xFFFF0000u); }

// 16B store at 4B alignment (CDNA supports dword-aligned dwordx4 global access)
__device__ __forceinline__ void store4u(float* p, f32x4 v) {
    asm volatile("global_store_dwordx4 %0, %1, off" :: "v"(p), "v"(v) : "memory");
}

// async global -> LDS, 16B per lane (dest = uniform base + lane*16)
__device__ __forceinline__ void gload16(const char* g, char* l) {
    __builtin_amdgcn_global_load_lds(
        (const __attribute__((address_space(1))) void*)g,
        (__attribute__((address_space(3))) void*)l, 16, 0, 0);
}

__device__ __forceinline__ bf16x8 ldfragS(const char* s, int f, int lane) {
    return *(const bf16x8*)(s + f * 1024 + (size_t)lane * 16);  // ds_read_b128 offset:f*1024
}
__device__ __forceinline__ bf16x8 mkfrag(const uint32_t* w) {
    union { uint32_t u[4]; bf16x8 f; } u;
    u.u[0] = w[0]; u.u[1] = w[1]; u.u[2] = w[2]; u.u[3] = w[3]; return u.f;
}

// ---------------- prep: build weight fragments + compact bias pages in ws ----------------
// frag index map (per z, each frag = 64 lanes x 16B):
//  0..3  W0hi (t, ks=0, k=d pad32, col24=b0)   4..7  W0lo
//  8..15 W1hi (t*2+ks)  16..23 W1lo  24..31 W2hi  32..39 W2lo
// 40..47 W2T  48..55 W1T  56..59 W0T (natural rows d, t*2+ks)
// bias page per z: 3 sel (b1,b2,Wout) x 64 floats, idx = q*16 + t*4 + r -> vec[magicRow(t,4q+r)]
__global__ void prep_kernel(const float* __restrict__ W0, const float* __restrict__ b0,
                            const float* __restrict__ W1, const float* __restrict__ W2,
                            const float* __restrict__ b1, const float* __restrict__ b2,
                            const float* __restrict__ Wout, char* __restrict__ ws)
{
    int idx = blockIdx.x * 256 + threadIdx.x;
    const int NFRAGL = 60 * 64 * 8;  // 30720
    if (idx < NFRAGL) {
        int z = idx / (60 * 64);
        int rem = idx % (60 * 64);
        int f = rem >> 6, l = rem & 63;
        int q = l >> 4, i = l & 15;
        uint32_t bits[8];
        #pragma unroll
        for (int e = 0; e < 8; ++e) {
            int kk = q * 8 + e;      // 0..31 within K-step
            float c = 0.f; bool lo = false;
            if (f < 8) {                       // W0 (K=24 + bias col 24)
                int t = f & 3; lo = (f >= 4);
                int o = magicRow(t, i);
                if (kk < 24) c = W0[(z * 64 + o) * 24 + kk];
                else if (kk == 24) c = b0[z * 64 + o];
            } else if (f < 24) {               // W1[g,h], o=g, k=h
                int g = (f - 8) & 7; lo = (f >= 16);
                int t = g >> 1, ks = g & 1, k = ks * 32 + kk;
                int o = magicRow(t, i);
                c = W1[(z * 64 + o) * 64 + k];
            } else if (f < 40) {               // W2[g,h]
                int g = (f - 24) & 7; lo = (f >= 32);
                int t = g >> 1, ks = g & 1, k = ks * 32 + kk;
                int o = magicRow(t, i);
                c = W2[(z * 64 + o) * 64 + k];
            } else if (f < 48) {               // W2T: o=h, k=g
                int g = f - 40; int t = g >> 1, ks = g & 1, k = ks * 32 + kk;
                int o = magicRow(t, i);
                c = W2[(z * 64 + k) * 64 + o];
            } else if (f < 56) {               // W1T
                int g = f - 48; int t = g >> 1, ks = g & 1, k = ks * 32 + kk;
                int o = magicRow(t, i);
                c = W1[(z * 64 + k) * 64 + o];
            } else {                           // W0T: o=d (natural), k=h
                int g = f - 56; int t = g >> 1, ks = g & 1, k = ks * 32 + kk;
                int o = t * 16 + i;
                c = (o < 24) ? W0[(z * 64 + k) * 24 + o] : 0.f;
            }
            if (lo) {
                uint32_t hb = rn16(c);
                float hf = __builtin_bit_cast(float, hb << 16);
                bits[e] = rn16(c - hf);
            } else bits[e] = rn16(c);
        }
        uint4 w;
        w.x = bits[0] | (bits[1] << 16);
        w.y = bits[2] | (bits[3] << 16);
        w.z = bits[4] | (bits[5] << 16);
        w.w = bits[6] | (bits[7] << 16);
        uint4* dst = (uint4*)(ws + (size_t)z * FRAG_Z + (size_t)f * 1024);
        dst[l] = w;
    } else if (idx < NFRAGL + 1536) {
        int j2 = idx - NFRAGL;
        int z = j2 / 192, rem = j2 % 192, sel = rem >> 6, l = rem & 63;
        int q = l >> 4, t = (l >> 2) & 3, r = l & 3;
        const float* vec = (sel == 0) ? b1 + z * 64 : (sel == 1) ? b2 + z * 64 : Wout + z * 64;
        ((float*)(ws + BIAS2_BASE))[z * 192 + sel * 64 + l] = vec[magicRow(t, 4 * q + r)];
    }
}

// ---------------- main kernel: 512 threads, one z per block, two-stage 40KB LDS ----------------
__global__ __launch_bounds__(512, 4)
void flow_main(const float* __restrict__ x, const float* __restrict__ bout,
               const char* __restrict__ ws, float* __restrict__ out,
               float* __restrict__ partial)
{
    const int lane = threadIdx.x & 63;
    const int wv   = threadIdx.x >> 6;   // 0..7
    const int q    = lane >> 4;
    const int iN   = lane & 15;
    const int blk  = blockIdx.x;    // 0..255
    const int z    = blockIdx.y;    // 0..7
    const int rowstart = blk * 256 + wv * 32;

    __shared__ __align__(16) char smem[40 * 1024];   // stage1: frags 0..39; stage2: frags 40..59 -> bytes 0..20K

    const char* gz = ws + (size_t)z * FRAG_Z;
    const char* gbias = ws + BIAS2_BASE + (size_t)z * 768;

    // ---- stage 1: forward frags 0..39 (5 per wave), issued before input pack ----
    #pragma unroll
    for (int i = 0; i < 5; ++i) {
        int f = wv * 5 + i;
        gload16(gz + f * 1024 + lane * 16, smem + f * 1024 + lane * 16);
    }

    // ---- input frags, split hi/lo (overlaps with staging) ----
    uint32_t bhi[2][4], blo[2][4];
    #pragma unroll
    for (int rt = 0; rt < 2; ++rt) {
        int n = rowstart + rt * 16 + iN;
        int b = n >> 9, t = n & 511;
        if (q < 3) {
            const float4* xp = (const float4*)(x + (size_t)(b * LEN + t) * 8 + q * 8);
            float4 A = xp[0], B = xp[1];
            float vv[8] = {A.x, A.y, A.z, A.w, B.x, B.y, B.z, B.w};
            #pragma unroll
            for (int p = 0; p < 4; ++p) {
                uint32_t hi = cvtpk(vv[2 * p], vv[2 * p + 1]);
                bhi[rt][p] = hi;
                blo[rt][p] = cvtpk(vv[2 * p] - lowf(hi), vv[2 * p + 1] - highf(hi));
            }
        } else {   // k=24 -> 1.0 (bias slot), rest 0
            bhi[rt][0] = 0x00003F80u; bhi[rt][1] = bhi[rt][2] = bhi[rt][3] = 0;
            blo[rt][0] = blo[rt][1] = blo[rt][2] = blo[rt][3] = 0;
        }
    }
    float boutz = bout[z];

    __syncthreads();   // drains vmcnt -> forward frags visible to all waves

    float asld = 0.f;
    f32x4 acc[2][4];

    // ---------- L0: h0 = W0 * full (+bias via k=24) ----------
    {
        bf16x8 wf[4];
        #pragma unroll
        for (int t = 0; t < 4; ++t) wf[t] = ldfragS(smem, t, lane);
        #pragma unroll
        for (int rt = 0; rt < 2; ++rt) {
            bf16x8 bh = mkfrag(bhi[rt]), bl = mkfrag(blo[rt]);
            #pragma unroll
            for (int t = 0; t < 4; ++t) {
                f32x4 a = {0.f, 0.f, 0.f, 0.f};
                a = MFMA16(wf[t], bh, a, 0, 0, 0);
                a = MFMA16(wf[t], bl, a, 0, 0, 0);
                acc[rt][t] = a;
            }
        }
        #pragma unroll
        for (int t = 0; t < 4; ++t) wf[t] = ldfragS(smem, 4 + t, lane);  // W0lo
        #pragma unroll
        for (int rt = 0; rt < 2; ++rt) {
            bf16x8 bh = mkfrag(bhi[rt]);
            #pragma unroll
            for (int t = 0; t < 4; ++t)
                acc[rt][t] = MFMA16(wf[t], bh, acc[rt][t], 0, 0, 0);
        }
    }
    // leaky + split-pack a0
    uint32_t a0h[2][8], a0l[2][8];
    #pragma unroll
    for (int rt = 0; rt < 2; ++rt) {
        #pragma unroll
        for (int t = 0; t < 4; ++t)
            #pragma unroll
            for (int r = 0; r < 4; ++r) {
                float v = acc[rt][t][r];
                acc[rt][t][r] = fmaxf(v, 0.2f * v);
            }
        #pragma unroll
        for (int ks = 0; ks < 2; ++ks)
            #pragma unroll
            for (int wd = 0; wd < 4; ++wd) {
                int tt = 2 * ks + (wd >> 1), rr = (wd & 1) * 2;
                float v0 = acc[rt][tt][rr], v1 = acc[rt][tt][rr + 1];
                uint32_t hi = cvtpk(v0, v1);
                a0h[rt][ks * 4 + wd] = hi;
                a0l[rt][ks * 4 + wd] = cvtpk(v0 - lowf(hi), v1 - highf(hi));
            }
    }

    // ---------- L1 ----------
    {
        union { float4 v; f32x4 a; } bb[4];
        const float4* bp = (const float4*)(gbias + 0 * 256 + q * 64);
        #pragma unroll
        for (int t = 0; t < 4; ++t) bb[t].v = bp[t];
        bf16x8 wf[8];
        #pragma unroll
        for (int g = 0; g < 8; ++g) wf[g] = ldfragS(smem, 8 + g, lane);
        #pragma unroll
        for (int rt = 0; rt < 2; ++rt)
            #pragma unroll
            for (int t = 0; t < 4; ++t) {
                f32x4 a = bb[t].a;
                #pragma unroll
                for (int ks = 0; ks < 2; ++ks) {
                    a = MFMA16(wf[t * 2 + ks], mkfrag(&a0h[rt][ks * 4]), a, 0, 0, 0);
                    a = MFMA16(wf[t * 2 + ks], mkfrag(&a0l[rt][ks * 4]), a, 0, 0, 0);
                }
                acc[rt][t] = a;
            }
        #pragma unroll
        for (int g = 0; g < 8; ++g) wf[g] = ldfragS(smem, 16 + g, lane);  // W1lo
        #pragma unroll
        for (int rt = 0; rt < 2; ++rt)
            #pragma unroll
            for (int t = 0; t < 4; ++t) {
                f32x4 a = acc[rt][t];
                #pragma unroll
                for (int ks = 0; ks < 2; ++ks)
                    a = MFMA16(wf[t * 2 + ks], mkfrag(&a0h[rt][ks * 4]), a, 0, 0, 0);
                acc[rt][t] = a;
            }
    }
    // leaky + split-pack a1 (keep a0h for d0 signs)
    uint32_t a1h[2][8], a1l[2][8];
    #pragma unroll
    for (int rt = 0; rt < 2; ++rt) {
        #pragma unroll
        for (int t = 0; t < 4; ++t)
            #pragma unroll
            for (int r = 0; r < 4; ++r) {
                float v = acc[rt][t][r];
                acc[rt][t][r] = fmaxf(v, 0.2f * v);
            }
        #pragma unroll
        for (int ks = 0; ks < 2; ++ks)
            #pragma unroll
            for (int wd = 0; wd < 4; ++wd) {
                int tt = 2 * ks + (wd >> 1), rr = (wd & 1) * 2;
                float v0 = acc[rt][tt][rr], v1 = acc[rt][tt][rr + 1];
                uint32_t hi = cvtpk(v0, v1);
                a1h[rt][ks * 4 + wd] = hi;
                a1l[rt][ks * 4 + wd] = cvtpk(v0 - lowf(hi), v1 - highf(hi));
            }
    }

    __syncthreads();   // all waves done reading frags 0..23 -> safe to overwrite bytes 0..20K

    // ---- stage 2: backward frags 40..59 -> LDS bytes 0..20K (j = wv, wv+8, wv+16) ----
    #pragma unroll
    for (int k = 0; k < 3; ++k) {
        int jj = wv + 8 * k;
        if (jj < 20)
            gload16(gz + (40 + jj) * 1024 + lane * 16, smem + jj * 1024 + lane * 16);
    }

    // ---------- L2 (frags 24..39, untouched by stage 2) ----------
    {
        union { float4 v; f32x4 a; } bb[4];
        const float4* bp = (const float4*)(gbias + 1 * 256 + q * 64);
        #pragma unroll
        for (int t = 0; t < 4; ++t) bb[t].v = bp[t];
        bf16x8 wf[8];
        #pragma unroll
        for (int g = 0; g < 8; ++g) wf[g] = ldfragS(smem, 24 + g, lane);
        #pragma unroll
        for (int rt = 0; rt < 2; ++rt)
            #pragma unroll
            for (int t = 0; t < 4; ++t) {
                f32x4 a = bb[t].a;
                #pragma unroll
                for (int ks = 0; ks < 2; ++ks) {
                    a = MFMA16(wf[t * 2 + ks], mkfrag(&a1h[rt][ks * 4]), a, 0, 0, 0);
                    a = MFMA16(wf[t * 2 + ks], mkfrag(&a1l[rt][ks * 4]), a, 0, 0, 0);
                }
                acc[rt][t] = a;
            }
        #pragma unroll
        for (int g = 0; g < 8; ++g) wf[g] = ldfragS(smem, 32 + g, lane);  // W2lo
        #pragma unroll
        for (int rt = 0; rt < 2; ++rt)
            #pragma unroll
            for (int t = 0; t < 4; ++t) {
                f32x4 a = acc[rt][t];
                #pragma unroll
                for (int ks = 0; ks < 2; ++ks)
                    a = MFMA16(wf[t * 2 + ks], mkfrag(&a1h[rt][ks * 4]), a, 0, 0, 0);
                acc[rt][t] = a;
            }
    }

    // ---------- out + t2 = d2*Wout (t2v is exactly the reference d2∘Wout) ----------
    float wl[16];
    {
        const float4* wp = (const float4*)(gbias + 2 * 256 + q * 64);
        #pragma unroll
        for (int t = 0; t < 4; ++t) {
            float4 v = wp[t];
            wl[t * 4 + 0] = v.x; wl[t * 4 + 1] = v.y; wl[t * 4 + 2] = v.z; wl[t * 4 + 3] = v.w;
        }
    }
    float ov[2];
    uint32_t t2p[2][8];
    #pragma unroll
    for (int rt = 0; rt < 2; ++rt) {
        float o = 0.f;
        float t2v[16];
        #pragma unroll
        for (int t = 0; t < 4; ++t)
            #pragma unroll
            for (int r = 0; r < 4; ++r) {
                float h = acc[rt][t][r];
                float w = wl[t * 4 + r];
                float tv = (h > 0.f) ? w : 0.2f * w;
                t2v[t * 4 + r] = tv;
                o = fmaf(h, tv, o);     // h * (d2*w) == a2 * w
            }
        #pragma unroll
        for (int ks = 0; ks < 2; ++ks)
            #pragma unroll
            for (int wd = 0; wd < 4; ++wd) {
                int tt = 2 * ks + (wd >> 1), rr = (wd & 1) * 2;
                t2p[rt][ks * 4 + wd] = cvtpk(t2v[tt * 4 + rr], t2v[tt * 4 + rr + 1]);
            }
        o += __shfl_xor(o, 16);
        o += __shfl_xor(o, 32);
        ov[rt] = o + boutz;
    }
    if (q == 0) {
        out[(size_t)(rowstart + 0 * 16 + iN) * 8 + z] = ov[0];
        out[(size_t)(rowstart + 1 * 16 + iN) * 8 + z] = ov[1];
    }

    __syncthreads();   // drains stage-2 vmcnt -> backward frags visible

    // ---------- G1 = W2T * t2, then *d1 (W2T at LDS 0..7) ----------
    uint32_t g1p[2][8];
    {
        bf16x8 wf[8];
        #pragma unroll
        for (int g = 0; g < 8; ++g) wf[g] = ldfragS(smem, g, lane);
        #pragma unroll
        for (int rt = 0; rt < 2; ++rt)
            #pragma unroll
            for (int t = 0; t < 4; ++t) {
                f32x4 a = {0.f, 0.f, 0.f, 0.f};
                #pragma unroll
                for (int ks = 0; ks < 2; ++ks)
                    a = MFMA16(wf[t * 2 + ks], mkfrag(&t2p[rt][ks * 4]), a, 0, 0, 0);
                acc[rt][t] = a;
            }
        #pragma unroll
        for (int rt = 0; rt < 2; ++rt) {
            #pragma unroll
            for (int t = 0; t < 4; ++t)
                #pragma unroll
                for (int r = 0; r < 4; ++r) {
                    uint32_t pw = a1h[rt][(t >> 1) * 4 + (t & 1) * 2 + (r >> 1)];
                    uint32_t neg = (pw >> (15 + 16 * (r & 1))) & 1u;
                    acc[rt][t][r] *= neg ? 0.2f : 1.0f;
                }
            #pragma unroll
            for (int ks = 0; ks < 2; ++ks)
                #pragma unroll
                for (int wd = 0; wd < 4; ++wd) {
                    int tt = 2 * ks + (wd >> 1), rr = (wd & 1) * 2;
                    g1p[rt][ks * 4 + wd] = cvtpk(acc[rt][tt][rr], acc[rt][tt][rr + 1]);
                }
        }
    }
    // ---------- G0 = W1T * g1, then *d0 (W1T at LDS 8..15) ----------
    uint32_t g0p[2][8];
    {
        bf16x8 wf[8];
        #pragma unroll
        for (int g = 0; g < 8; ++g) wf[g] = ldfragS(smem, 8 + g, lane);
        #pragma unroll
        for (int rt = 0; rt < 2; ++rt)
            #pragma unroll
            for (int t = 0; t < 4; ++t) {
                f32x4 a = {0.f, 0.f, 0.f, 0.f};
                #pragma unroll
                for (int ks = 0; ks < 2; ++ks)
                    a = MFMA16(wf[t * 2 + ks], mkfrag(&g1p[rt][ks * 4]), a, 0, 0, 0);
                acc[rt][t] = a;
            }
        #pragma unroll
        for (int rt = 0; rt < 2; ++rt) {
            #pragma unroll
            for (int t = 0; t < 4; ++t)
                #pragma unroll
                for (int r = 0; r < 4; ++r) {
                    uint32_t pw = a0h[rt][(t >> 1) * 4 + (t & 1) * 2 + (r >> 1)];
                    uint32_t neg = (pw >> (15 + 16 * (r & 1))) & 1u;
                    acc[rt][t][r] *= neg ? 0.2f : 1.0f;
                }
            #pragma unroll
            for (int ks = 0; ks < 2; ++ks)
                #pragma unroll
                for (int wd = 0; wd < 4; ++wd) {
                    int tt = 2 * ks + (wd >> 1), rr = (wd & 1) * 2;
                    g0p[rt][ks * 4 + wd] = cvtpk(acc[rt][tt][rr], acc[rt][tt][rr + 1]);
                }
        }
    }
    // ---------- Jac = W0T * g0 (W0T at LDS 16..19) ----------
    f32x4 aj[2][2];
    {
        bf16x8 wf[4];
        #pragma unroll
        for (int g = 0; g < 4; ++g) wf[g] = ldfragS(smem, 16 + g, lane);
        #pragma unroll
        for (int rt = 0; rt < 2; ++rt)
            #pragma unroll
            for (int t = 0; t < 2; ++t) {
                f32x4 a = {0.f, 0.f, 0.f, 0.f};
                #pragma unroll
                for (int ks = 0; ks < 2; ++ks)
                    a = MFMA16(wf[t * 2 + ks], mkfrag(&g0p[rt][ks * 4]), a, 0, 0, 0);
                aj[rt][t] = a;
            }
    }

    // diag -> log|.| (diag d=16+z lives in tile1, reg z&3, lanes q==z>>2)
    {
        int zr = z & 3, zq = z >> 2;
        #pragma unroll
        for (int rt = 0; rt < 2; ++rt) {
            f32x4 d4 = aj[rt][1];
            float dv = (zr == 0) ? d4[0] : (zr == 1) ? d4[1] : (zr == 2) ? d4[2] : d4[3];
            float lg = __logf(fabsf(dv));
            asld += (q == zq) ? lg : 0.f;
        }
    }

    // ---------- hist_jac: direct global stores (no LDS transpose) ----------
    {
        uint32_t DW = 16 + z;
        size_t hb = 524416 + (size_t)65536 * (16 * z + (z * (z - 1)) / 2);
        #pragma unroll
        for (int rt = 0; rt < 2; ++rt) {
            int n = rowstart + rt * 16 + iN;
            float* rowp = out + hb + (size_t)n * DW;
            store4u(rowp + q * 4, aj[rt][0]);      // 16B at 4B alignment
            #pragma unroll
            for (int r = 0; r < 4; ++r)
                if (q * 4 + r < z) rowp[16 + q * 4 + r] = aj[rt][1][r];
        }
    }

    // deterministic wave-sum of log|diag|, one partial per (block, wave)
    #pragma unroll
    for (int off = 1; off < 64; off <<= 1) asld += __shfl_xor(asld, off);
    if (lane == 0) partial[(size_t)(z * 256 + blk) * 8 + wv] = asld;
}

// sld[b] = deterministic fixed-order sum of its 128 partials
__global__ void reduce_sld(const float* __restrict__ partial, float* __restrict__ sld)
{
    int b = threadIdx.x;   // 0..127
    float s = 0.f;
    #pragma unroll
    for (int z = 0; z < 8; ++z)
        #pragma unroll
        for (int k = 0; k < 2; ++k)
            #pragma unroll
            for (int w = 0; w < 8; ++w)
                s += partial[(size_t)(z * 256 + b * 2 + k) * 8 + w];
    sld[b] = s;
}

extern "C" void kernel_launch(void* const* d_in, const int* in_sizes, int n_in,
                              void* d_out, int out_size, void* d_ws, size_t ws_size,
                              hipStream_t stream) {
    const float* x    = (const float*)d_in[0];
    const float* W0   = (const float*)d_in[1];
    const float* b0   = (const float*)d_in[2];
    const float* W1   = (const float*)d_in[3];
    const float* b1   = (const float*)d_in[4];
    const float* W2   = (const float*)d_in[5];
    const float* b2   = (const float*)d_in[6];
    const float* Wout = (const float*)d_in[7];
    const float* bout = (const float*)d_in[8];

    char* ws = (char*)d_ws;
    float* out = (float*)d_out;
    float* partial = (float*)(ws + PART_BASE);

    prep_kernel<<<126, 256, 0, stream>>>(W0, b0, W1, W2, b1, b2, Wout, ws);
    flow_main<<<dim3(256, 8), 512, 0, stream>>>(x, bout, (const char*)ws, out, partial);
    reduce_sld<<<1, 128, 0, stream>>>((const float*)partial, out + (size_t)Nn * Zc);
}

// Round 11
// 60.173 us; speedup vs baseline: 4.5386x; 1.0004x over previous
//
#include <hip/hip_runtime.h>
#include <hip/hip_bf16.h>
#include <math.h>

typedef short bf16x8 __attribute__((ext_vector_type(8)));
typedef float f32x4 __attribute__((ext_vector_type(4)));

#define MFMA16 __builtin_amdgcn_mfma_f32_16x16x32_bf16

constexpr int Zc = 8, Hc = 64, Dc = 24, Tc = 512, Bc = 128, LEN = 514;
constexpr int Nn = Bc * Tc;                // 65536
constexpr size_t FRAG_Z  = 60 * 1024;      // bytes of frags per z
constexpr size_t BIAS2_BASE = 8 * FRAG_Z;              // 491520 (8 z * 768B compact bias)
constexpr size_t PART_BASE  = BIAS2_BASE + 8 * 768;    // 497664 (+64KB partials)

// magic row permutation: tile t, tile-row i (0..15) -> actual output index
__device__ __forceinline__ int magicRow(int t, int i) {
    return 32 * (t >> 1) + 8 * (i >> 2) + 4 * (t & 1) + (i & 3);
}
__device__ __forceinline__ uint32_t rn16(float v) {  // f32 -> bf16 bits (RNE)
    uint32_t u = __builtin_bit_cast(uint32_t, v);
    return ((u + 0x7FFFu + ((u >> 16) & 1u)) >> 16) & 0xFFFFu;
}
// main-kernel pack: single HW instruction, RNE. lo = bf16(a), hi = bf16(b)
__device__ __forceinline__ uint32_t cvtpk(float a, float b) {
    uint32_t r;
    asm("v_cvt_pk_bf16_f32 %0, %1, %2" : "=v"(r) : "v"(a), "v"(b));
    return r;
}
__device__ __forceinline__ float lowf(uint32_t u)  { return __builtin_bit_cast(float, u << 16); }
__device__ __forceinline__ float highf(uint32_t u) { return __builtin_bit_cast(float, u & 0xFFFF0000u); }

// 16B store at 4B alignment (CDNA supports dword-aligned dwordx4 global access)
__device__ __forceinline__ void store4u(float* p, f32x4 v) {
    asm volatile("global_store_dwordx4 %0, %1, off" :: "v"(p), "v"(v) : "memory");
}

// async global -> LDS, 16B per lane (dest = uniform base + lane*16)
__device__ __forceinline__ void gload16(const char* g, char* l) {
    __builtin_amdgcn_global_load_lds(
        (const __attribute__((address_space(1))) void*)g,
        (__attribute__((address_space(3))) void*)l, 16, 0, 0);
}

__device__ __forceinline__ bf16x8 ldfragS(const char* s, int f, int lane) {
    return *(const bf16x8*)(s + f * 1024 + (size_t)lane * 16);  // ds_read_b128 offset:f*1024
}
__device__ __forceinline__ bf16x8 mkfrag(const uint32_t* w) {
    union { uint32_t u[4]; bf16x8 f; } u;
    u.u[0] = w[0]; u.u[1] = w[1]; u.u[2] = w[2]; u.u[3] = w[3]; return u.f;
}

// ---------------- prep: build weight fragments + compact bias pages in ws ----------------
// frag index map (per z, each frag = 64 lanes x 16B):
//  0..3  W0hi (t, ks=0, k=d pad32, col24=b0)   4..7  W0lo
//  8..15 W1hi (t*2+ks)  16..23 W1lo  24..31 W2hi  32..39 W2lo
// 40..47 W2T  48..55 W1T  56..59 W0T (natural rows d, t*2+ks)
// bias page per z: 3 sel (b1,b2,Wout) x 64 floats, idx = q*16 + t*4 + r -> vec[magicRow(t,4q+r)]
__global__ void prep_kernel(const float* __restrict__ W0, const float* __restrict__ b0,
                            const float* __restrict__ W1, const float* __restrict__ W2,
                            const float* __restrict__ b1, const float* __restrict__ b2,
                            const float* __restrict__ Wout, char* __restrict__ ws)
{
    int idx = blockIdx.x * 256 + threadIdx.x;
    const int NFRAGL = 60 * 64 * 8;  // 30720
    if (idx < NFRAGL) {
        int z = idx / (60 * 64);
        int rem = idx % (60 * 64);
        int f = rem >> 6, l = rem & 63;
        int q = l >> 4, i = l & 15;
        uint32_t bits[8];
        #pragma unroll
        for (int e = 0; e < 8; ++e) {
            int kk = q * 8 + e;      // 0..31 within K-step
            float c = 0.f; bool lo = false;
            if (f < 8) {                       // W0 (K=24 + bias col 24)
                int t = f & 3; lo = (f >= 4);
                int o = magicRow(t, i);
                if (kk < 24) c = W0[(z * 64 + o) * 24 + kk];
                else if (kk == 24) c = b0[z * 64 + o];
            } else if (f < 24) {               // W1[g,h], o=g, k=h
                int g = (f - 8) & 7; lo = (f >= 16);
                int t = g >> 1, ks = g & 1, k = ks * 32 + kk;
                int o = magicRow(t, i);
                c = W1[(z * 64 + o) * 64 + k];
            } else if (f < 40) {               // W2[g,h]
                int g = (f - 24) & 7; lo = (f >= 32);
                int t = g >> 1, ks = g & 1, k = ks * 32 + kk;
                int o = magicRow(t, i);
                c = W2[(z * 64 + o) * 64 + k];
            } else if (f < 48) {               // W2T: o=h, k=g
                int g = f - 40; int t = g >> 1, ks = g & 1, k = ks * 32 + kk;
                int o = magicRow(t, i);
                c = W2[(z * 64 + k) * 64 + o];
            } else if (f < 56) {               // W1T
                int g = f - 48; int t = g >> 1, ks = g & 1, k = ks * 32 + kk;
                int o = magicRow(t, i);
                c = W1[(z * 64 + k) * 64 + o];
            } else {                           // W0T: o=d (natural), k=h
                int g = f - 56; int t = g >> 1, ks = g & 1, k = ks * 32 + kk;
                int o = t * 16 + i;
                c = (o < 24) ? W0[(z * 64 + k) * 24 + o] : 0.f;
            }
            if (lo) {
                uint32_t hb = rn16(c);
                float hf = __builtin_bit_cast(float, hb << 16);
                bits[e] = rn16(c - hf);
            } else bits[e] = rn16(c);
        }
        uint4 w;
        w.x = bits[0] | (bits[1] << 16);
        w.y = bits[2] | (bits[3] << 16);
        w.z = bits[4] | (bits[5] << 16);
        w.w = bits[6] | (bits[7] << 16);
        uint4* dst = (uint4*)(ws + (size_t)z * FRAG_Z + (size_t)f * 1024);
        dst[l] = w;
    } else if (idx < NFRAGL + 1536) {
        int j2 = idx - NFRAGL;
        int z = j2 / 192, rem = j2 % 192, sel = rem >> 6, l = rem & 63;
        int q = l >> 4, t = (l >> 2) & 3, r = l & 3;
        const float* vec = (sel == 0) ? b1 + z * 64 : (sel == 1) ? b2 + z * 64 : Wout + z * 64;
        ((float*)(ws + BIAS2_BASE))[z * 192 + sel * 64 + l] = vec[magicRow(t, 4 * q + r)];
    }
}

// ---------------- main kernel: 512 threads, one z per block, two-stage 40KB LDS ----------------
__global__ __launch_bounds__(512, 4)
void flow_main(const float* __restrict__ x, const float* __restrict__ bout,
               const char* __restrict__ ws, float* __restrict__ out,
               float* __restrict__ partial)
{
    const int lane = threadIdx.x & 63;
    const int wv   = threadIdx.x >> 6;   // 0..7
    const int q    = lane >> 4;
    const int iN   = lane & 15;
    const int blk  = blockIdx.x;    // 0..255
    const int z    = blockIdx.y;    // 0..7
    const int rowstart = blk * 256 + wv * 32;

    __shared__ __align__(16) char smem[40 * 1024];   // stage1: frags 0..39; stage2: frags 40..59 -> bytes 0..20K

    const char* gz = ws + (size_t)z * FRAG_Z;
    const char* gbias = ws + BIAS2_BASE + (size_t)z * 768;

    // ---- stage 1: forward frags 0..39 (5 per wave), issued before input pack ----
    #pragma unroll
    for (int i = 0; i < 5; ++i) {
        int f = wv * 5 + i;
        gload16(gz + f * 1024 + lane * 16, smem + f * 1024 + lane * 16);
    }

    // ---- input frags, split hi/lo (overlaps with staging) ----
    uint32_t bhi[2][4], blo[2][4];
    #pragma unroll
    for (int rt = 0; rt < 2; ++rt) {
        int n = rowstart + rt * 16 + iN;
        int b = n >> 9, t = n & 511;
        if (q < 3) {
            const float4* xp = (const float4*)(x + (size_t)(b * LEN + t) * 8 + q * 8);
            float4 A = xp[0], B = xp[1];
            float vv[8] = {A.x, A.y, A.z, A.w, B.x, B.y, B.z, B.w};
            #pragma unroll
            for (int p = 0; p < 4; ++p) {
                uint32_t hi = cvtpk(vv[2 * p], vv[2 * p + 1]);
                bhi[rt][p] = hi;
                blo[rt][p] = cvtpk(vv[2 * p] - lowf(hi), vv[2 * p + 1] - highf(hi));
            }
        } else {   // k=24 -> 1.0 (bias slot), rest 0
            bhi[rt][0] = 0x00003F80u; bhi[rt][1] = bhi[rt][2] = bhi[rt][3] = 0;
            blo[rt][0] = blo[rt][1] = blo[rt][2] = blo[rt][3] = 0;
        }
    }
    float boutz = bout[z];

    __syncthreads();   // drains vmcnt -> forward frags visible to all waves

    float asld = 0.f;
    f32x4 acc[2][4];

    // ---------- L0: h0 = W0 * full (+bias via k=24) ----------
    {
        bf16x8 wf[4];
        #pragma unroll
        for (int t = 0; t < 4; ++t) wf[t] = ldfragS(smem, t, lane);
        __builtin_amdgcn_s_setprio(1);
        #pragma unroll
        for (int rt = 0; rt < 2; ++rt) {
            bf16x8 bh = mkfrag(bhi[rt]), bl = mkfrag(blo[rt]);
            #pragma unroll
            for (int t = 0; t < 4; ++t) {
                f32x4 a = {0.f, 0.f, 0.f, 0.f};
                a = MFMA16(wf[t], bh, a, 0, 0, 0);
                a = MFMA16(wf[t], bl, a, 0, 0, 0);
                acc[rt][t] = a;
            }
        }
        __builtin_amdgcn_s_setprio(0);
        #pragma unroll
        for (int t = 0; t < 4; ++t) wf[t] = ldfragS(smem, 4 + t, lane);  // W0lo
        __builtin_amdgcn_s_setprio(1);
        #pragma unroll
        for (int rt = 0; rt < 2; ++rt) {
            bf16x8 bh = mkfrag(bhi[rt]);
            #pragma unroll
            for (int t = 0; t < 4; ++t)
                acc[rt][t] = MFMA16(wf[t], bh, acc[rt][t], 0, 0, 0);
        }
        __builtin_amdgcn_s_setprio(0);
    }
    // leaky + split-pack a0
    uint32_t a0h[2][8], a0l[2][8];
    #pragma unroll
    for (int rt = 0; rt < 2; ++rt) {
        #pragma unroll
        for (int t = 0; t < 4; ++t)
            #pragma unroll
            for (int r = 0; r < 4; ++r) {
                float v = acc[rt][t][r];
                acc[rt][t][r] = fmaxf(v, 0.2f * v);
            }
        #pragma unroll
        for (int ks = 0; ks < 2; ++ks)
            #pragma unroll
            for (int wd = 0; wd < 4; ++wd) {
                int tt = 2 * ks + (wd >> 1), rr = (wd & 1) * 2;
                float v0 = acc[rt][tt][rr], v1 = acc[rt][tt][rr + 1];
                uint32_t hi = cvtpk(v0, v1);
                a0h[rt][ks * 4 + wd] = hi;
                a0l[rt][ks * 4 + wd] = cvtpk(v0 - lowf(hi), v1 - highf(hi));
            }
    }

    // ---------- L1 ----------
    {
        union { float4 v; f32x4 a; } bb[4];
        const float4* bp = (const float4*)(gbias + 0 * 256 + q * 64);
        #pragma unroll
        for (int t = 0; t < 4; ++t) bb[t].v = bp[t];
        bf16x8 wf[8];
        #pragma unroll
        for (int g = 0; g < 8; ++g) wf[g] = ldfragS(smem, 8 + g, lane);
        __builtin_amdgcn_s_setprio(1);
        #pragma unroll
        for (int rt = 0; rt < 2; ++rt)
            #pragma unroll
            for (int t = 0; t < 4; ++t) {
                f32x4 a = bb[t].a;
                #pragma unroll
                for (int ks = 0; ks < 2; ++ks) {
                    a = MFMA16(wf[t * 2 + ks], mkfrag(&a0h[rt][ks * 4]), a, 0, 0, 0);
                    a = MFMA16(wf[t * 2 + ks], mkfrag(&a0l[rt][ks * 4]), a, 0, 0, 0);
                }
                acc[rt][t] = a;
            }
        __builtin_amdgcn_s_setprio(0);
        #pragma unroll
        for (int g = 0; g < 8; ++g) wf[g] = ldfragS(smem, 16 + g, lane);  // W1lo
        __builtin_amdgcn_s_setprio(1);
        #pragma unroll
        for (int rt = 0; rt < 2; ++rt)
            #pragma unroll
            for (int t = 0; t < 4; ++t) {
                f32x4 a = acc[rt][t];
                #pragma unroll
                for (int ks = 0; ks < 2; ++ks)
                    a = MFMA16(wf[t * 2 + ks], mkfrag(&a0h[rt][ks * 4]), a, 0, 0, 0);
                acc[rt][t] = a;
            }
        __builtin_amdgcn_s_setprio(0);
    }
    // leaky + split-pack a1 (keep a0h for d0 signs)
    uint32_t a1h[2][8], a1l[2][8];
    #pragma unroll
    for (int rt = 0; rt < 2; ++rt) {
        #pragma unroll
        for (int t = 0; t < 4; ++t)
            #pragma unroll
            for (int r = 0; r < 4; ++r) {
                float v = acc[rt][t][r];
                acc[rt][t][r] = fmaxf(v, 0.2f * v);
            }
        #pragma unroll
        for (int ks = 0; ks < 2; ++ks)
            #pragma unroll
            for (int wd = 0; wd < 4; ++wd) {
                int tt = 2 * ks + (wd >> 1), rr = (wd & 1) * 2;
                float v0 = acc[rt][tt][rr], v1 = acc[rt][tt][rr + 1];
                uint32_t hi = cvtpk(v0, v1);
                a1h[rt][ks * 4 + wd] = hi;
                a1l[rt][ks * 4 + wd] = cvtpk(v0 - lowf(hi), v1 - highf(hi));
            }
    }

    __syncthreads();   // all waves done reading frags 0..23 -> safe to overwrite bytes 0..20K

    // ---- stage 2: backward frags 40..59 -> LDS bytes 0..20K (j = wv, wv+8, wv+16) ----
    #pragma unroll
    for (int k = 0; k < 3; ++k) {
        int jj = wv + 8 * k;
        if (jj < 20)
            gload16(gz + (40 + jj) * 1024 + lane * 16, smem + jj * 1024 + lane * 16);
    }

    // ---------- L2 (frags 24..39, untouched by stage 2) ----------
    {
        union { float4 v; f32x4 a; } bb[4];
        const float4* bp = (const float4*)(gbias + 1 * 256 + q * 64);
        #pragma unroll
        for (int t = 0; t < 4; ++t) bb[t].v = bp[t];
        bf16x8 wf[8];
        #pragma unroll
        for (int g = 0; g < 8; ++g) wf[g] = ldfragS(smem, 24 + g, lane);
        __builtin_amdgcn_s_setprio(1);
        #pragma unroll
        for (int rt = 0; rt < 2; ++rt)
            #pragma unroll
            for (int t = 0; t < 4; ++t) {
                f32x4 a = bb[t].a;
                #pragma unroll
                for (int ks = 0; ks < 2; ++ks) {
                    a = MFMA16(wf[t * 2 + ks], mkfrag(&a1h[rt][ks * 4]), a, 0, 0, 0);
                    a = MFMA16(wf[t * 2 + ks], mkfrag(&a1l[rt][ks * 4]), a, 0, 0, 0);
                }
                acc[rt][t] = a;
            }
        __builtin_amdgcn_s_setprio(0);
        #pragma unroll
        for (int g = 0; g < 8; ++g) wf[g] = ldfragS(smem, 32 + g, lane);  // W2lo
        __builtin_amdgcn_s_setprio(1);
        #pragma unroll
        for (int rt = 0; rt < 2; ++rt)
            #pragma unroll
            for (int t = 0; t < 4; ++t) {
                f32x4 a = acc[rt][t];
                #pragma unroll
                for (int ks = 0; ks < 2; ++ks)
                    a = MFMA16(wf[t * 2 + ks], mkfrag(&a1h[rt][ks * 4]), a, 0, 0, 0);
                acc[rt][t] = a;
            }
        __builtin_amdgcn_s_setprio(0);
    }

    // ---------- out + t2 = d2*Wout (t2v is exactly the reference d2∘Wout) ----------
    float wl[16];
    {
        const float4* wp = (const float4*)(gbias + 2 * 256 + q * 64);
        #pragma unroll
        for (int t = 0; t < 4; ++t) {
            float4 v = wp[t];
            wl[t * 4 + 0] = v.x; wl[t * 4 + 1] = v.y; wl[t * 4 + 2] = v.z; wl[t * 4 + 3] = v.w;
        }
    }
    float ov[2];
    uint32_t t2p[2][8];
    #pragma unroll
    for (int rt = 0; rt < 2; ++rt) {
        float o = 0.f;
        float t2v[16];
        #pragma unroll
        for (int t = 0; t < 4; ++t)
            #pragma unroll
            for (int r = 0; r < 4; ++r) {
                float h = acc[rt][t][r];
                float w = wl[t * 4 + r];
                float tv = (h > 0.f) ? w : 0.2f * w;
                t2v[t * 4 + r] = tv;
                o = fmaf(h, tv, o);     // h * (d2*w) == a2 * w
            }
        #pragma unroll
        for (int ks = 0; ks < 2; ++ks)
            #pragma unroll
            for (int wd = 0; wd < 4; ++wd) {
                int tt = 2 * ks + (wd >> 1), rr = (wd & 1) * 2;
                t2p[rt][ks * 4 + wd] = cvtpk(t2v[tt * 4 + rr], t2v[tt * 4 + rr + 1]);
            }
        o += __shfl_xor(o, 16);
        o += __shfl_xor(o, 32);
        ov[rt] = o + boutz;
    }
    if (q == 0) {
        out[(size_t)(rowstart + 0 * 16 + iN) * 8 + z] = ov[0];
        out[(size_t)(rowstart + 1 * 16 + iN) * 8 + z] = ov[1];
    }

    __syncthreads();   // drains stage-2 vmcnt -> backward frags visible

    // ---------- G1 = W2T * t2, then *d1 (W2T at LDS 0..7) ----------
    uint32_t g1p[2][8];
    {
        bf16x8 wf[8];
        #pragma unroll
        for (int g = 0; g < 8; ++g) wf[g] = ldfragS(smem, g, lane);
        __builtin_amdgcn_s_setprio(1);
        #pragma unroll
        for (int rt = 0; rt < 2; ++rt)
            #pragma unroll
            for (int t = 0; t < 4; ++t) {
                f32x4 a = {0.f, 0.f, 0.f, 0.f};
                #pragma unroll
                for (int ks = 0; ks < 2; ++ks)
                    a = MFMA16(wf[t * 2 + ks], mkfrag(&t2p[rt][ks * 4]), a, 0, 0, 0);
                acc[rt][t] = a;
            }
        __builtin_amdgcn_s_setprio(0);
        #pragma unroll
        for (int rt = 0; rt < 2; ++rt) {
            #pragma unroll
            for (int t = 0; t < 4; ++t)
                #pragma unroll
                for (int r = 0; r < 4; ++r) {
                    uint32_t pw = a1h[rt][(t >> 1) * 4 + (t & 1) * 2 + (r >> 1)];
                    uint32_t neg = (pw >> (15 + 16 * (r & 1))) & 1u;
                    acc[rt][t][r] *= neg ? 0.2f : 1.0f;
                }
            #pragma unroll
            for (int ks = 0; ks < 2; ++ks)
                #pragma unroll
                for (int wd = 0; wd < 4; ++wd) {
                    int tt = 2 * ks + (wd >> 1), rr = (wd & 1) * 2;
                    g1p[rt][ks * 4 + wd] = cvtpk(acc[rt][tt][rr], acc[rt][tt][rr + 1]);
                }
        }
    }
    // ---------- G0 = W1T * g1, then *d0 (W1T at LDS 8..15) ----------
    uint32_t g0p[2][8];
    {
        bf16x8 wf[8];
        #pragma unroll
        for (int g = 0; g < 8; ++g) wf[g] = ldfragS(smem, 8 + g, lane);
        __builtin_amdgcn_s_setprio(1);
        #pragma unroll
        for (int rt = 0; rt < 2; ++rt)
            #pragma unroll
            for (int t = 0; t < 4; ++t) {
                f32x4 a = {0.f, 0.f, 0.f, 0.f};
                #pragma unroll
                for (int ks = 0; ks < 2; ++ks)
                    a = MFMA16(wf[t * 2 + ks], mkfrag(&g1p[rt][ks * 4]), a, 0, 0, 0);
                acc[rt][t] = a;
            }
        __builtin_amdgcn_s_setprio(0);
        #pragma unroll
        for (int rt = 0; rt < 2; ++rt) {
            #pragma unroll
            for (int t = 0; t < 4; ++t)
                #pragma unroll
                for (int r = 0; r < 4; ++r) {
                    uint32_t pw = a0h[rt][(t >> 1) * 4 + (t & 1) * 2 + (r >> 1)];
                    uint32_t neg = (pw >> (15 + 16 * (r & 1))) & 1u;
                    acc[rt][t][r] *= neg ? 0.2f : 1.0f;
                }
            #pragma unroll
            for (int ks = 0; ks < 2; ++ks)
                #pragma unroll
                for (int wd = 0; wd < 4; ++wd) {
                    int tt = 2 * ks + (wd >> 1), rr = (wd & 1) * 2;
                    g0p[rt][ks * 4 + wd] = cvtpk(acc[rt][tt][rr], acc[rt][tt][rr + 1]);
                }
        }
    }
    // ---------- Jac = W0T * g0 (W0T at LDS 16..19) ----------
    f32x4 aj[2][2];
    {
        bf16x8 wf[4];
        #pragma unroll
        for (int g = 0; g < 4; ++g) wf[g] = ldfragS(smem, 16 + g, lane);
        __builtin_amdgcn_s_setprio(1);
        #pragma unroll
        for (int rt = 0; rt < 2; ++rt)
            #pragma unroll
            for (int t = 0; t < 2; ++t) {
                f32x4 a = {0.f, 0.f, 0.f, 0.f};
                #pragma unroll
                for (int ks = 0; ks < 2; ++ks)
                    a = MFMA16(wf[t * 2 + ks], mkfrag(&g0p[rt][ks * 4]), a, 0, 0, 0);
                aj[rt][t] = a;
            }
        __builtin_amdgcn_s_setprio(0);
    }

    // diag -> log|.| (diag d=16+z lives in tile1, reg z&3, lanes q==z>>2)
    {
        int zr = z & 3, zq = z >> 2;
        #pragma unroll
        for (int rt = 0; rt < 2; ++rt) {
            f32x4 d4 = aj[rt][1];
            float dv = (zr == 0) ? d4[0] : (zr == 1) ? d4[1] : (zr == 2) ? d4[2] : d4[3];
            float lg = __logf(fabsf(dv));
            asld += (q == zq) ? lg : 0.f;
        }
    }

    // ---------- hist_jac: direct global stores (no LDS transpose) ----------
    {
        uint32_t DW = 16 + z;
        size_t hb = 524416 + (size_t)65536 * (16 * z + (z * (z - 1)) / 2);
        #pragma unroll
        for (int rt = 0; rt < 2; ++rt) {
            int n = rowstart + rt * 16 + iN;
            float* rowp = out + hb + (size_t)n * DW;
            store4u(rowp + q * 4, aj[rt][0]);      // 16B at 4B alignment
            #pragma unroll
            for (int r = 0; r < 4; ++r)
                if (q * 4 + r < z) rowp[16 + q * 4 + r] = aj[rt][1][r];
        }
    }

    // deterministic wave-sum of log|diag|, one partial per (block, wave)
    #pragma unroll
    for (int off = 1; off < 64; off <<= 1) asld += __shfl_xor(asld, off);
    if (lane == 0) partial[(size_t)(z * 256 + blk) * 8 + wv] = asld;
}

// sld[b] = deterministic fixed-order sum of its 128 partials
__global__ void reduce_sld(const float* __restrict__ partial, float* __restrict__ sld)
{
    int b = threadIdx.x;   // 0..127
    float s = 0.f;
    #pragma unroll
    for (int z = 0; z < 8; ++z)
        #pragma unroll
        for (int k = 0; k < 2; ++k)
            #pragma unroll
            for (int w = 0; w < 8; ++w)
                s += partial[(size_t)(z * 256 + b * 2 + k) * 8 + w];
    sld[b] = s;
}

extern "C" void kernel_launch(void* const* d_in, const int* in_sizes, int n_in,
                              void* d_out, int out_size, void* d_ws, size_t ws_size,
                              hipStream_t stream) {
    const float* x    = (const float*)d_in[0];
    const float* W0   = (const float*)d_in[1];
    const float* b0   = (const float*)d_in[2];
    const float* W1   = (const float*)d_in[3];
    const float* b1   = (const float*)d_in[4];
    const float* W2   = (const float*)d_in[5];
    const float* b2   = (const float*)d_in[6];
    const float* Wout = (const float*)d_in[7];
    const float* bout = (const float*)d_in[8];

    char* ws = (char*)d_ws;
    float* out = (float*)d_out;
    float* partial = (float*)(ws + PART_BASE);

    prep_kernel<<<126, 256, 0, stream>>>(W0, b0, W1, W2, b1, b2, Wout, ws);
    flow_main<<<dim3(256, 8), 512, 0, stream>>>(x, bout, (const char*)ws, out, partial);
    reduce_sld<<<1, 128, 0, stream>>>((const float*)partial, out + (size_t)Nn * Zc);
}

// Round 13
// 46.309 us; speedup vs baseline: 5.8974x; 1.2994x over previous
//
#include <hip/hip_runtime.h>
#include <hip/hip_bf16.h>
#include <math.h>

typedef _Float16 f16x8 __attribute__((ext_vector_type(8)));
typedef float f32x4 __attribute__((ext_vector_type(4)));

#define MFMAH __builtin_amdgcn_mfma_f32_16x16x32_f16

constexpr int Zc = 8, Hc = 64, Dc = 24, Tc = 512, Bc = 128, LEN = 514;
constexpr int Nn = Bc * Tc;                // 65536
constexpr size_t FRAG_Z  = 40 * 1024;      // 40 fp16 frags per z
constexpr size_t BIAS2_BASE = 8 * FRAG_Z;              // 327680 (8 z * 768B f32 bias pages)
constexpr size_t PART_BASE  = BIAS2_BASE + 8 * 768;    // 333824 (+64KB partials)

// magic row permutation: tile t, tile-row i (0..15) -> actual output index
__device__ __forceinline__ int magicRow(int t, int i) {
    return 32 * (t >> 1) + 8 * (i >> 2) + 4 * (t & 1) + (i & 3);
}
__device__ __forceinline__ uint32_t h16(float v) {   // f32 -> fp16 bits (RNE)
    union { _Float16 h; uint16_t u; } c; c.h = (_Float16)v; return (uint32_t)c.u;
}
// pack 2 f32 -> 2 fp16 in one instr (RTZ)
__device__ __forceinline__ uint32_t cvtpkh(float a, float b) {
    return __builtin_bit_cast(uint32_t, __builtin_amdgcn_cvt_pkrtz(a, b));
}

// 16B store at 4B alignment (CDNA supports dword-aligned dwordx4 global access)
__device__ __forceinline__ void store4u(float* p, f32x4 v) {
    asm volatile("global_store_dwordx4 %0, %1, off" :: "v"(p), "v"(v) : "memory");
}

// async global -> LDS, 16B per lane (dest = uniform base + lane*16)
__device__ __forceinline__ void gload16(const char* g, char* l) {
    __builtin_amdgcn_global_load_lds(
        (const __attribute__((address_space(1))) void*)g,
        (__attribute__((address_space(3))) void*)l, 16, 0, 0);
}

__device__ __forceinline__ f16x8 ldfragH(const char* s, int f, int lane) {
    return *(const f16x8*)(s + f * 1024 + (size_t)lane * 16);  // ds_read_b128 offset:f*1024
}
__device__ __forceinline__ f16x8 mkfragh(const uint32_t* w) {
    union { uint32_t u[4]; f16x8 f; } u;
    u.u[0] = w[0]; u.u[1] = w[1]; u.u[2] = w[2]; u.u[3] = w[3]; return u.f;
}

// ---------------- prep: build fp16 weight fragments + f32 bias pages in ws ----------------
// frag map (per z, each frag = 64 lanes x 16B = 1KB):
//  0..3   W0  (t, K=32: k<24 = W0, k==24 = b0, else 0)
//  4..11  W1  (g: t=g>>1, ks=g&1)      12..19 W2
// 20..27  W2T (o=h, k=g)               28..35 W1T
// 36..39  W0T (o=d natural rows, t*2+ks)
// bias page per z: 3 sel (b1,b2,Wout) x 64 f32, idx q*16+t*4+r -> vec[magicRow(t,4q+r)]
__global__ void prep_kernel(const float* __restrict__ W0, const float* __restrict__ b0,
                            const float* __restrict__ W1, const float* __restrict__ W2,
                            const float* __restrict__ b1, const float* __restrict__ b2,
                            const float* __restrict__ Wout, char* __restrict__ ws)
{
    int idx = blockIdx.x * 256 + threadIdx.x;
    const int NFRAGL = 40 * 64 * 8;  // 20480
    if (idx < NFRAGL) {
        int z = idx / (40 * 64);
        int rem = idx % (40 * 64);
        int f = rem >> 6, l = rem & 63;
        int q = l >> 4, i = l & 15;
        uint32_t bits[8];
        #pragma unroll
        for (int e = 0; e < 8; ++e) {
            int kk = q * 8 + e;      // 0..31 within K-step
            float c = 0.f;
            if (f < 4) {                       // W0 (K=24 + bias col 24)
                int t = f;
                int o = magicRow(t, i);
                if (kk < 24) c = W0[(z * 64 + o) * 24 + kk];
                else if (kk == 24) c = b0[z * 64 + o];
            } else if (f < 12) {               // W1[g,h], o=g, k=h
                int g = f - 4;
                int t = g >> 1, ks = g & 1, k = ks * 32 + kk;
                int o = magicRow(t, i);
                c = W1[(z * 64 + o) * 64 + k];
            } else if (f < 20) {               // W2[g,h]
                int g = f - 12;
                int t = g >> 1, ks = g & 1, k = ks * 32 + kk;
                int o = magicRow(t, i);
                c = W2[(z * 64 + o) * 64 + k];
            } else if (f < 28) {               // W2T: o=h, k=g
                int g = f - 20; int t = g >> 1, ks = g & 1, k = ks * 32 + kk;
                int o = magicRow(t, i);
                c = W2[(z * 64 + k) * 64 + o];
            } else if (f < 36) {               // W1T
                int g = f - 28; int t = g >> 1, ks = g & 1, k = ks * 32 + kk;
                int o = magicRow(t, i);
                c = W1[(z * 64 + k) * 64 + o];
            } else {                           // W0T: o=d (natural), k=h
                int g = f - 36; int t = g >> 1, ks = g & 1, k = ks * 32 + kk;
                int o = t * 16 + i;
                c = (o < 24) ? W0[(z * 64 + k) * 24 + o] : 0.f;
            }
            bits[e] = h16(c);
        }
        uint4 w;
        w.x = bits[0] | (bits[1] << 16);
        w.y = bits[2] | (bits[3] << 16);
        w.z = bits[4] | (bits[5] << 16);
        w.w = bits[6] | (bits[7] << 16);
        uint4* dst = (uint4*)(ws + (size_t)z * FRAG_Z + (size_t)f * 1024);
        dst[l] = w;
    } else if (idx < NFRAGL + 1536) {
        int j2 = idx - NFRAGL;
        int z = j2 / 192, rem = j2 % 192, sel = rem >> 6, l = rem & 63;
        int q = l >> 4, t = (l >> 2) & 3, r = l & 3;
        const float* vec = (sel == 0) ? b1 + z * 64 : (sel == 1) ? b2 + z * 64 : Wout + z * 64;
        ((float*)(ws + BIAS2_BASE))[z * 192 + sel * 64 + l] = vec[magicRow(t, 4 * q + r)];
    }
}

// ---------------- main kernel: 512 threads, one z per block, single-stage 40KB LDS ----------------
__global__ __launch_bounds__(512, 4)
void flow_main(const float* __restrict__ x, const float* __restrict__ bout,
               const char* __restrict__ ws, float* __restrict__ out,
               float* __restrict__ partial)
{
    const int lane = threadIdx.x & 63;
    const int wv   = threadIdx.x >> 6;   // 0..7
    const int q    = lane >> 4;
    const int iN   = lane & 15;
    const int blk  = blockIdx.x;    // 0..255
    const int z    = blockIdx.y;    // 0..7
    const int rowstart = blk * 256 + wv * 32;

    __shared__ __align__(16) char smem[40 * 1024];   // all 40 fp16 frags

    const char* gz = ws + (size_t)z * FRAG_Z;
    const char* gbias = ws + BIAS2_BASE + (size_t)z * 768;

    // ---- stage ALL 40 frags (5 per wave), issued before input pack ----
    #pragma unroll
    for (int i = 0; i < 5; ++i) {
        int f = wv * 5 + i;
        gload16(gz + f * 1024 + lane * 16, smem + f * 1024 + lane * 16);
    }

    // ---- input frags (fp16, single term) — overlaps with staging ----
    uint32_t bh[2][4];
    #pragma unroll
    for (int rt = 0; rt < 2; ++rt) {
        int n = rowstart + rt * 16 + iN;
        int b = n >> 9, t = n & 511;
        if (q < 3) {
            const float4* xp = (const float4*)(x + (size_t)(b * LEN + t) * 8 + q * 8);
            float4 A = xp[0], B = xp[1];
            bh[rt][0] = cvtpkh(A.x, A.y);
            bh[rt][1] = cvtpkh(A.z, A.w);
            bh[rt][2] = cvtpkh(B.x, B.y);
            bh[rt][3] = cvtpkh(B.z, B.w);
        } else {   // k=24 -> 1.0 (bias slot), rest 0
            bh[rt][0] = 0x00003C00u; bh[rt][1] = bh[rt][2] = bh[rt][3] = 0;
        }
    }
    float boutz = bout[z];

    __syncthreads();   // drains vmcnt -> all frags visible to all waves

    float asld = 0.f;
    f32x4 acc[2][4];

    // ---------- L0: h0 = W0 * full (+bias via k=24) ----------
    {
        f16x8 wf[4];
        #pragma unroll
        for (int t = 0; t < 4; ++t) wf[t] = ldfragH(smem, t, lane);
        #pragma unroll
        for (int rt = 0; rt < 2; ++rt) {
            f16x8 bb = mkfragh(bh[rt]);
            #pragma unroll
            for (int t = 0; t < 4; ++t) {
                f32x4 a = {0.f, 0.f, 0.f, 0.f};
                acc[rt][t] = MFMAH(wf[t], bb, a, 0, 0, 0);
            }
        }
    }
    // leaky + pack a0 (fp16)
    uint32_t a0p[2][8];
    #pragma unroll
    for (int rt = 0; rt < 2; ++rt) {
        #pragma unroll
        for (int t = 0; t < 4; ++t)
            #pragma unroll
            for (int r = 0; r < 4; ++r) {
                float v = acc[rt][t][r];
                acc[rt][t][r] = fmaxf(v, 0.2f * v);
            }
        #pragma unroll
        for (int ks = 0; ks < 2; ++ks)
            #pragma unroll
            for (int wd = 0; wd < 4; ++wd) {
                int tt = 2 * ks + (wd >> 1), rr = (wd & 1) * 2;
                a0p[rt][ks * 4 + wd] = cvtpkh(acc[rt][tt][rr], acc[rt][tt][rr + 1]);
            }
    }

    // ---------- L1 (frags 4..11) ----------
    {
        union { float4 v; f32x4 a; } bb[4];
        const float4* bp = (const float4*)(gbias + 0 * 256 + q * 64);
        #pragma unroll
        for (int t = 0; t < 4; ++t) bb[t].v = bp[t];
        f16x8 wf[8];
        #pragma unroll
        for (int g = 0; g < 8; ++g) wf[g] = ldfragH(smem, 4 + g, lane);
        #pragma unroll
        for (int rt = 0; rt < 2; ++rt)
            #pragma unroll
            for (int t = 0; t < 4; ++t) {
                f32x4 a = bb[t].a;
                #pragma unroll
                for (int ks = 0; ks < 2; ++ks)
                    a = MFMAH(wf[t * 2 + ks], mkfragh(&a0p[rt][ks * 4]), a, 0, 0, 0);
                acc[rt][t] = a;
            }
    }
    // leaky + pack a1 (keep a0p for d0 signs)
    uint32_t a1p[2][8];
    #pragma unroll
    for (int rt = 0; rt < 2; ++rt) {
        #pragma unroll
        for (int t = 0; t < 4; ++t)
            #pragma unroll
            for (int r = 0; r < 4; ++r) {
                float v = acc[rt][t][r];
                acc[rt][t][r] = fmaxf(v, 0.2f * v);
            }
        #pragma unroll
        for (int ks = 0; ks < 2; ++ks)
            #pragma unroll
            for (int wd = 0; wd < 4; ++wd) {
                int tt = 2 * ks + (wd >> 1), rr = (wd & 1) * 2;
                a1p[rt][ks * 4 + wd] = cvtpkh(acc[rt][tt][rr], acc[rt][tt][rr + 1]);
            }
    }

    // ---------- L2 (frags 12..19; h2 stays pre-activation in acc) ----------
    {
        union { float4 v; f32x4 a; } bb[4];
        const float4* bp = (const float4*)(gbias + 1 * 256 + q * 64);
        #pragma unroll
        for (int t = 0; t < 4; ++t) bb[t].v = bp[t];
        f16x8 wf[8];
        #pragma unroll
        for (int g = 0; g < 8; ++g) wf[g] = ldfragH(smem, 12 + g, lane);
        #pragma unroll
        for (int rt = 0; rt < 2; ++rt)
            #pragma unroll
            for (int t = 0; t < 4; ++t) {
                f32x4 a = bb[t].a;
                #pragma unroll
                for (int ks = 0; ks < 2; ++ks)
                    a = MFMAH(wf[t * 2 + ks], mkfragh(&a1p[rt][ks * 4]), a, 0, 0, 0);
                acc[rt][t] = a;
            }
    }

    // ---------- out + t2 = d2*Wout ----------
    float wl[16];
    {
        const float4* wp = (const float4*)(gbias + 2 * 256 + q * 64);
        #pragma unroll
        for (int t = 0; t < 4; ++t) {
            float4 v = wp[t];
            wl[t * 4 + 0] = v.x; wl[t * 4 + 1] = v.y; wl[t * 4 + 2] = v.z; wl[t * 4 + 3] = v.w;
        }
    }
    float ov[2];
    uint32_t t2p[2][8];
    #pragma unroll
    for (int rt = 0; rt < 2; ++rt) {
        float o = 0.f;
        float t2v[16];
        #pragma unroll
        for (int t = 0; t < 4; ++t)
            #pragma unroll
            for (int r = 0; r < 4; ++r) {
                float h = acc[rt][t][r];
                float w = wl[t * 4 + r];
                float tv = (h > 0.f) ? w : 0.2f * w;
                t2v[t * 4 + r] = tv;
                o = fmaf(h, tv, o);     // h * (d2*w) == a2 * w
            }
        #pragma unroll
        for (int ks = 0; ks < 2; ++ks)
            #pragma unroll
            for (int wd = 0; wd < 4; ++wd) {
                int tt = 2 * ks + (wd >> 1), rr = (wd & 1) * 2;
                t2p[rt][ks * 4 + wd] = cvtpkh(t2v[tt * 4 + rr], t2v[tt * 4 + rr + 1]);
            }
        o += __shfl_xor(o, 16);
        o += __shfl_xor(o, 32);
        ov[rt] = o + boutz;
    }
    if (q == 0) {
        out[(size_t)(rowstart + 0 * 16 + iN) * 8 + z] = ov[0];
        out[(size_t)(rowstart + 1 * 16 + iN) * 8 + z] = ov[1];
    }

    // ---------- G1 = W2T * t2, then *d1 (frags 20..27) ----------
    uint32_t g1p[2][8];
    {
        f16x8 wf[8];
        #pragma unroll
        for (int g = 0; g < 8; ++g) wf[g] = ldfragH(smem, 20 + g, lane);
        #pragma unroll
        for (int rt = 0; rt < 2; ++rt)
            #pragma unroll
            for (int t = 0; t < 4; ++t) {
                f32x4 a = {0.f, 0.f, 0.f, 0.f};
                #pragma unroll
                for (int ks = 0; ks < 2; ++ks)
                    a = MFMAH(wf[t * 2 + ks], mkfragh(&t2p[rt][ks * 4]), a, 0, 0, 0);
                acc[rt][t] = a;
            }
        #pragma unroll
        for (int rt = 0; rt < 2; ++rt) {
            #pragma unroll
            for (int t = 0; t < 4; ++t)
                #pragma unroll
                for (int r = 0; r < 4; ++r) {
                    uint32_t pw = a1p[rt][(t >> 1) * 4 + (t & 1) * 2 + (r >> 1)];
                    uint32_t neg = (pw >> (15 + 16 * (r & 1))) & 1u;
                    acc[rt][t][r] *= neg ? 0.2f : 1.0f;
                }
            #pragma unroll
            for (int ks = 0; ks < 2; ++ks)
                #pragma unroll
                for (int wd = 0; wd < 4; ++wd) {
                    int tt = 2 * ks + (wd >> 1), rr = (wd & 1) * 2;
                    g1p[rt][ks * 4 + wd] = cvtpkh(acc[rt][tt][rr], acc[rt][tt][rr + 1]);
                }
        }
    }
    // ---------- G0 = W1T * g1, then *d0 (frags 28..35) ----------
    uint32_t g0p[2][8];
    {
        f16x8 wf[8];
        #pragma unroll
        for (int g = 0; g < 8; ++g) wf[g] = ldfragH(smem, 28 + g, lane);
        #pragma unroll
        for (int rt = 0; rt < 2; ++rt)
            #pragma unroll
            for (int t = 0; t < 4; ++t) {
                f32x4 a = {0.f, 0.f, 0.f, 0.f};
                #pragma unroll
                for (int ks = 0; ks < 2; ++ks)
                    a = MFMAH(wf[t * 2 + ks], mkfragh(&g1p[rt][ks * 4]), a, 0, 0, 0);
                acc[rt][t] = a;
            }
        #pragma unroll
        for (int rt = 0; rt < 2; ++rt) {
            #pragma unroll
            for (int t = 0; t < 4; ++t)
                #pragma unroll
                for (int r = 0; r < 4; ++r) {
                    uint32_t pw = a0p[rt][(t >> 1) * 4 + (t & 1) * 2 + (r >> 1)];
                    uint32_t neg = (pw >> (15 + 16 * (r & 1))) & 1u;
                    acc[rt][t][r] *= neg ? 0.2f : 1.0f;
                }
            #pragma unroll
            for (int ks = 0; ks < 2; ++ks)
                #pragma unroll
                for (int wd = 0; wd < 4; ++wd) {
                    int tt = 2 * ks + (wd >> 1), rr = (wd & 1) * 2;
                    g0p[rt][ks * 4 + wd] = cvtpkh(acc[rt][tt][rr], acc[rt][tt][rr + 1]);
                }
        }
    }
    // ---------- Jac = W0T * g0 (frags 36..39) ----------
    f32x4 aj[2][2];
    {
        f16x8 wf[4];
        #pragma unroll
        for (int g = 0; g < 4; ++g) wf[g] = ldfragH(smem, 36 + g, lane);
        #pragma unroll
        for (int rt = 0; rt < 2; ++rt)
            #pragma unroll
            for (int t = 0; t < 2; ++t) {
                f32x4 a = {0.f, 0.f, 0.f, 0.f};
                #pragma unroll
                for (int ks = 0; ks < 2; ++ks)
                    a = MFMAH(wf[t * 2 + ks], mkfragh(&g0p[rt][ks * 4]), a, 0, 0, 0);
                aj[rt][t] = a;
            }
    }

    // diag -> log|.| (diag d=16+z lives in tile1, reg z&3, lanes q==z>>2)
    {
        int zr = z & 3, zq = z >> 2;
        #pragma unroll
        for (int rt = 0; rt < 2; ++rt) {
            f32x4 d4 = aj[rt][1];
            float dv = (zr == 0) ? d4[0] : (zr == 1) ? d4[1] : (zr == 2) ? d4[2] : d4[3];
            float lg = __logf(fabsf(dv));
            asld += (q == zq) ? lg : 0.f;
        }
    }

    // ---------- hist_jac: direct global stores (no LDS transpose) ----------
    {
        uint32_t DW = 16 + z;
        size_t hb = 524416 + (size_t)65536 * (16 * z + (z * (z - 1)) / 2);
        #pragma unroll
        for (int rt = 0; rt < 2; ++rt) {
            int n = rowstart + rt * 16 + iN;
            float* rowp = out + hb + (size_t)n * DW;
            store4u(rowp + q * 4, aj[rt][0]);      // 16B at 4B alignment
            #pragma unroll
            for (int r = 0; r < 4; ++r)
                if (q * 4 + r < z) rowp[16 + q * 4 + r] = aj[rt][1][r];
        }
    }

    // deterministic wave-sum of log|diag|, one partial per (block, wave)
    #pragma unroll
    for (int off = 1; off < 64; off <<= 1) asld += __shfl_xor(asld, off);
    if (lane == 0) partial[(size_t)(z * 256 + blk) * 8 + wv] = asld;
}

// sld[b] = deterministic fixed-order sum of its 128 partials
__global__ void reduce_sld(const float* __restrict__ partial, float* __restrict__ sld)
{
    int b = threadIdx.x;   // 0..127
    float s = 0.f;
    #pragma unroll
    for (int z = 0; z < 8; ++z)
        #pragma unroll
        for (int k = 0; k < 2; ++k)
            #pragma unroll
            for (int w = 0; w < 8; ++w)
                s += partial[(size_t)(z * 256 + b * 2 + k) * 8 + w];
    sld[b] = s;
}

extern "C" void kernel_launch(void* const* d_in, const int* in_sizes, int n_in,
                              void* d_out, int out_size, void* d_ws, size_t ws_size,
                              hipStream_t stream) {
    const float* x    = (const float*)d_in[0];
    const float* W0   = (const float*)d_in[1];
    const float* b0   = (const float*)d_in[2];
    const float* W1   = (const float*)d_in[3];
    const float* b1   = (const float*)d_in[4];
    const float* W2   = (const float*)d_in[5];
    const float* b2   = (const float*)d_in[6];
    const float* Wout = (const float*)d_in[7];
    const float* bout = (const float*)d_in[8];

    char* ws = (char*)d_ws;
    float* out = (float*)d_out;
    float* partial = (float*)(ws + PART_BASE);

    prep_kernel<<<86, 256, 0, stream>>>(W0, b0, W1, W2, b1, b2, Wout, ws);
    flow_main<<<dim3(256, 8), 512, 0, stream>>>(x, bout, (const char*)ws, out, partial);
    reduce_sld<<<1, 128, 0, stream>>>((const float*)partial, out + (size_t)Nn * Zc);
}

// Round 14
// 45.781 us; speedup vs baseline: 5.9653x; 1.0115x over previous
//
#include <hip/hip_runtime.h>
#include <hip/hip_bf16.h>
#include <math.h>

typedef _Float16 f16x8 __attribute__((ext_vector_type(8)));
typedef _Float16 f16x2n __attribute__((ext_vector_type(2)));
typedef float f32x4 __attribute__((ext_vector_type(4)));

#define MFMAH __builtin_amdgcn_mfma_f32_16x16x32_f16

constexpr int Zc = 8, Hc = 64, Dc = 24, Tc = 512, Bc = 128, LEN = 514;
constexpr int Nn = Bc * Tc;                // 65536
constexpr size_t FRAG_Z  = 40 * 1024;      // 40 fp16 frags per z
constexpr size_t BIAS2_BASE = 8 * FRAG_Z;              // 327680 (8 z * 768B f32 bias pages)
constexpr size_t PART_BASE  = BIAS2_BASE + 8 * 768;    // 333824 (+64KB partials)

// magic row permutation: tile t, tile-row i (0..15) -> actual output index
__device__ __forceinline__ int magicRow(int t, int i) {
    return 32 * (t >> 1) + 8 * (i >> 2) + 4 * (t & 1) + (i & 3);
}
__device__ __forceinline__ uint32_t h16(float v) {   // f32 -> fp16 bits (RNE)
    union { _Float16 h; uint16_t u; } c; c.h = (_Float16)v; return (uint32_t)c.u;
}
// pack 2 f32 -> 2 fp16 in one instr (RTZ)
__device__ __forceinline__ uint32_t cvtpkh(float a, float b) {
    return __builtin_bit_cast(uint32_t, __builtin_amdgcn_cvt_pkrtz(a, b));
}
// packed fp16 multiply (v_pk_mul_f16)
__device__ __forceinline__ uint32_t pkmul(uint32_t a, uint32_t b) {
    f16x2n x = __builtin_bit_cast(f16x2n, a), y = __builtin_bit_cast(f16x2n, b);
    return __builtin_bit_cast(uint32_t, x * y);
}
// packed leaky-derivative multiplier from packed sign bits: 1.0 / 0.2 per half
__device__ __forceinline__ uint32_t dmask(uint32_t pw) {
    return 0x3C003C00u ^ (((pw & 0x80008000u) >> 15) * 0x0E66u);
}

// 16B store at 4B alignment (CDNA supports dword-aligned dwordx4 global access)
__device__ __forceinline__ void store4u(float* p, f32x4 v) {
    asm volatile("global_store_dwordx4 %0, %1, off" :: "v"(p), "v"(v) : "memory");
}

// async global -> LDS, 16B per lane (dest = uniform base + lane*16)
__device__ __forceinline__ void gload16(const char* g, char* l) {
    __builtin_amdgcn_global_load_lds(
        (const __attribute__((address_space(1))) void*)g,
        (__attribute__((address_space(3))) void*)l, 16, 0, 0);
}

__device__ __forceinline__ f16x8 ldfragH(const char* s, int f, int lane) {
    return *(const f16x8*)(s + f * 1024 + (size_t)lane * 16);  // ds_read_b128 offset:f*1024
}
__device__ __forceinline__ f16x8 mkfragh(const uint32_t* w) {
    union { uint32_t u[4]; f16x8 f; } u;
    u.u[0] = w[0]; u.u[1] = w[1]; u.u[2] = w[2]; u.u[3] = w[3]; return u.f;
}

// ---------------- prep: build fp16 weight fragments + f32 bias pages in ws ----------------
// frag map (per z, each frag = 64 lanes x 16B = 1KB):
//  0..3   W0  (t, K=32: k<24 = W0, k==24 = b0, else 0)
//  4..11  W1  (g: t=g>>1, ks=g&1)      12..19 W2
// 20..27  W2T (o=h, k=g)               28..35 W1T
// 36..39  W0T (o=d natural rows, t*2+ks)
// bias page per z: 3 sel (b1,b2,Wout) x 64 f32, idx q*16+t*4+r -> vec[magicRow(t,4q+r)]
__global__ void prep_kernel(const float* __restrict__ W0, const float* __restrict__ b0,
                            const float* __restrict__ W1, const float* __restrict__ W2,
                            const float* __restrict__ b1, const float* __restrict__ b2,
                            const float* __restrict__ Wout, char* __restrict__ ws)
{
    int idx = blockIdx.x * 256 + threadIdx.x;
    const int NFRAGL = 40 * 64 * 8;  // 20480
    if (idx < NFRAGL) {
        int z = idx / (40 * 64);
        int rem = idx % (40 * 64);
        int f = rem >> 6, l = rem & 63;
        int q = l >> 4, i = l & 15;
        uint32_t bits[8];
        #pragma unroll
        for (int e = 0; e < 8; ++e) {
            int kk = q * 8 + e;      // 0..31 within K-step
            float c = 0.f;
            if (f < 4) {                       // W0 (K=24 + bias col 24)
                int t = f;
                int o = magicRow(t, i);
                if (kk < 24) c = W0[(z * 64 + o) * 24 + kk];
                else if (kk == 24) c = b0[z * 64 + o];
            } else if (f < 12) {               // W1[g,h], o=g, k=h
                int g = f - 4;
                int t = g >> 1, ks = g & 1, k = ks * 32 + kk;
                int o = magicRow(t, i);
                c = W1[(z * 64 + o) * 64 + k];
            } else if (f < 20) {               // W2[g,h]
                int g = f - 12;
                int t = g >> 1, ks = g & 1, k = ks * 32 + kk;
                int o = magicRow(t, i);
                c = W2[(z * 64 + o) * 64 + k];
            } else if (f < 28) {               // W2T: o=h, k=g
                int g = f - 20; int t = g >> 1, ks = g & 1, k = ks * 32 + kk;
                int o = magicRow(t, i);
                c = W2[(z * 64 + k) * 64 + o];
            } else if (f < 36) {               // W1T
                int g = f - 28; int t = g >> 1, ks = g & 1, k = ks * 32 + kk;
                int o = magicRow(t, i);
                c = W1[(z * 64 + k) * 64 + o];
            } else {                           // W0T: o=d (natural), k=h
                int g = f - 36; int t = g >> 1, ks = g & 1, k = ks * 32 + kk;
                int o = t * 16 + i;
                c = (o < 24) ? W0[(z * 64 + k) * 24 + o] : 0.f;
            }
            bits[e] = h16(c);
        }
        uint4 w;
        w.x = bits[0] | (bits[1] << 16);
        w.y = bits[2] | (bits[3] << 16);
        w.z = bits[4] | (bits[5] << 16);
        w.w = bits[6] | (bits[7] << 16);
        uint4* dst = (uint4*)(ws + (size_t)z * FRAG_Z + (size_t)f * 1024);
        dst[l] = w;
    } else if (idx < NFRAGL + 1536) {
        int j2 = idx - NFRAGL;
        int z = j2 / 192, rem = j2 % 192, sel = rem >> 6, l = rem & 63;
        int q = l >> 4, t = (l >> 2) & 3, r = l & 3;
        const float* vec = (sel == 0) ? b1 + z * 64 : (sel == 1) ? b2 + z * 64 : Wout + z * 64;
        ((float*)(ws + BIAS2_BASE))[z * 192 + sel * 64 + l] = vec[magicRow(t, 4 * q + r)];
    }
}

// ---------------- main kernel: 512 threads, one z per block, single-stage 40KB LDS ----------------
__global__ __launch_bounds__(512, 4)
void flow_main(const float* __restrict__ x, const float* __restrict__ bout,
               const char* __restrict__ ws, float* __restrict__ out,
               float* __restrict__ partial)
{
    const int lane = threadIdx.x & 63;
    const int wv   = threadIdx.x >> 6;   // 0..7
    const int q    = lane >> 4;
    const int iN   = lane & 15;
    const int blk  = blockIdx.x;    // 0..255
    const int z    = blockIdx.y;    // 0..7
    const int rowstart = blk * 256 + wv * 32;

    __shared__ __align__(16) char smem[40 * 1024];   // all 40 fp16 frags

    const char* gz = ws + (size_t)z * FRAG_Z;
    const char* gbias = ws + BIAS2_BASE + (size_t)z * 768;

    // ---- stage ALL 40 frags (5 per wave), issued before input pack ----
    #pragma unroll
    for (int i = 0; i < 5; ++i) {
        int f = wv * 5 + i;
        gload16(gz + f * 1024 + lane * 16, smem + f * 1024 + lane * 16);
    }

    // ---- input frags (fp16, single term) — overlaps with staging ----
    uint32_t bh[2][4];
    #pragma unroll
    for (int rt = 0; rt < 2; ++rt) {
        int n = rowstart + rt * 16 + iN;
        int b = n >> 9, t = n & 511;
        if (q < 3) {
            const float4* xp = (const float4*)(x + (size_t)(b * LEN + t) * 8 + q * 8);
            float4 A = xp[0], B = xp[1];
            bh[rt][0] = cvtpkh(A.x, A.y);
            bh[rt][1] = cvtpkh(A.z, A.w);
            bh[rt][2] = cvtpkh(B.x, B.y);
            bh[rt][3] = cvtpkh(B.z, B.w);
        } else {   // k=24 -> 1.0 (bias slot), rest 0
            bh[rt][0] = 0x00003C00u; bh[rt][1] = bh[rt][2] = bh[rt][3] = 0;
        }
    }
    float boutz = bout[z];

    __syncthreads();   // drains vmcnt -> all frags visible to all waves

    float asld = 0.f;
    f32x4 acc[2][4];

    // ---------- L0: h0 = W0 * full (+bias via k=24) ----------
    {
        f16x8 wf[4];
        #pragma unroll
        for (int t = 0; t < 4; ++t) wf[t] = ldfragH(smem, t, lane);
        #pragma unroll
        for (int rt = 0; rt < 2; ++rt) {
            f16x8 bb = mkfragh(bh[rt]);
            #pragma unroll
            for (int t = 0; t < 4; ++t) {
                f32x4 a = {0.f, 0.f, 0.f, 0.f};
                acc[rt][t] = MFMAH(wf[t], bb, a, 0, 0, 0);
            }
        }
    }
    // leaky + pack a0 (fp16)
    uint32_t a0p[2][8];
    #pragma unroll
    for (int rt = 0; rt < 2; ++rt) {
        #pragma unroll
        for (int t = 0; t < 4; ++t)
            #pragma unroll
            for (int r = 0; r < 4; ++r) {
                float v = acc[rt][t][r];
                acc[rt][t][r] = fmaxf(v, 0.2f * v);
            }
        #pragma unroll
        for (int ks = 0; ks < 2; ++ks)
            #pragma unroll
            for (int wd = 0; wd < 4; ++wd) {
                int tt = 2 * ks + (wd >> 1), rr = (wd & 1) * 2;
                a0p[rt][ks * 4 + wd] = cvtpkh(acc[rt][tt][rr], acc[rt][tt][rr + 1]);
            }
    }

    // ---------- L1 (frags 4..11) ----------
    {
        union { float4 v; f32x4 a; } bb[4];
        const float4* bp = (const float4*)(gbias + 0 * 256 + q * 64);
        #pragma unroll
        for (int t = 0; t < 4; ++t) bb[t].v = bp[t];
        f16x8 wf[8];
        #pragma unroll
        for (int g = 0; g < 8; ++g) wf[g] = ldfragH(smem, 4 + g, lane);
        #pragma unroll
        for (int rt = 0; rt < 2; ++rt)
            #pragma unroll
            for (int t = 0; t < 4; ++t) {
                f32x4 a = bb[t].a;
                #pragma unroll
                for (int ks = 0; ks < 2; ++ks)
                    a = MFMAH(wf[t * 2 + ks], mkfragh(&a0p[rt][ks * 4]), a, 0, 0, 0);
                acc[rt][t] = a;
            }
    }
    // leaky + pack a1 (keep a0p for d0 signs)
    uint32_t a1p[2][8];
    #pragma unroll
    for (int rt = 0; rt < 2; ++rt) {
        #pragma unroll
        for (int t = 0; t < 4; ++t)
            #pragma unroll
            for (int r = 0; r < 4; ++r) {
                float v = acc[rt][t][r];
                acc[rt][t][r] = fmaxf(v, 0.2f * v);
            }
        #pragma unroll
        for (int ks = 0; ks < 2; ++ks)
            #pragma unroll
            for (int wd = 0; wd < 4; ++wd) {
                int tt = 2 * ks + (wd >> 1), rr = (wd & 1) * 2;
                a1p[rt][ks * 4 + wd] = cvtpkh(acc[rt][tt][rr], acc[rt][tt][rr + 1]);
            }
    }

    // ---------- L2 (frags 12..19; h2 stays pre-activation in acc) ----------
    {
        union { float4 v; f32x4 a; } bb[4];
        const float4* bp = (const float4*)(gbias + 1 * 256 + q * 64);
        #pragma unroll
        for (int t = 0; t < 4; ++t) bb[t].v = bp[t];
        f16x8 wf[8];
        #pragma unroll
        for (int g = 0; g < 8; ++g) wf[g] = ldfragH(smem, 12 + g, lane);
        #pragma unroll
        for (int rt = 0; rt < 2; ++rt)
            #pragma unroll
            for (int t = 0; t < 4; ++t) {
                f32x4 a = bb[t].a;
                #pragma unroll
                for (int ks = 0; ks < 2; ++ks)
                    a = MFMAH(wf[t * 2 + ks], mkfragh(&a1p[rt][ks * 4]), a, 0, 0, 0);
                acc[rt][t] = a;
            }
    }

    // ---------- out + t2 = d2*Wout ----------
    float wl[16];
    {
        const float4* wp = (const float4*)(gbias + 2 * 256 + q * 64);
        #pragma unroll
        for (int t = 0; t < 4; ++t) {
            float4 v = wp[t];
            wl[t * 4 + 0] = v.x; wl[t * 4 + 1] = v.y; wl[t * 4 + 2] = v.z; wl[t * 4 + 3] = v.w;
        }
    }
    float ov[2];
    uint32_t t2p[2][8];
    #pragma unroll
    for (int rt = 0; rt < 2; ++rt) {
        float o = 0.f;
        float t2v[16];
        #pragma unroll
        for (int t = 0; t < 4; ++t)
            #pragma unroll
            for (int r = 0; r < 4; ++r) {
                float h = acc[rt][t][r];
                float w = wl[t * 4 + r];
                float tv = (h > 0.f) ? w : 0.2f * w;
                t2v[t * 4 + r] = tv;
                o = fmaf(h, tv, o);     // h * (d2*w) == a2 * w
            }
        #pragma unroll
        for (int ks = 0; ks < 2; ++ks)
            #pragma unroll
            for (int wd = 0; wd < 4; ++wd) {
                int tt = 2 * ks + (wd >> 1), rr = (wd & 1) * 2;
                t2p[rt][ks * 4 + wd] = cvtpkh(t2v[tt * 4 + rr], t2v[tt * 4 + rr + 1]);
            }
        o += __shfl_xor(o, 16);
        o += __shfl_xor(o, 32);
        ov[rt] = o + boutz;
    }
    if (q == 0) {
        out[(size_t)(rowstart + 0 * 16 + iN) * 8 + z] = ov[0];
        out[(size_t)(rowstart + 1 * 16 + iN) * 8 + z] = ov[1];
    }

    // ---------- G1 = W2T * t2, then *d1 via packed mask (frags 20..27) ----------
    uint32_t g1p[2][8];
    {
        f16x8 wf[8];
        #pragma unroll
        for (int g = 0; g < 8; ++g) wf[g] = ldfragH(smem, 20 + g, lane);
        #pragma unroll
        for (int rt = 0; rt < 2; ++rt)
            #pragma unroll
            for (int t = 0; t < 4; ++t) {
                f32x4 a = {0.f, 0.f, 0.f, 0.f};
                #pragma unroll
                for (int ks = 0; ks < 2; ++ks)
                    a = MFMAH(wf[t * 2 + ks], mkfragh(&t2p[rt][ks * 4]), a, 0, 0, 0);
                acc[rt][t] = a;
            }
        #pragma unroll
        for (int rt = 0; rt < 2; ++rt)
            #pragma unroll
            for (int ks = 0; ks < 2; ++ks)
                #pragma unroll
                for (int wd = 0; wd < 4; ++wd) {
                    int tt = 2 * ks + (wd >> 1), rr = (wd & 1) * 2;
                    uint32_t pw = a1p[rt][(tt >> 1) * 4 + (tt & 1) * 2 + (rr >> 1)];
                    uint32_t p = cvtpkh(acc[rt][tt][rr], acc[rt][tt][rr + 1]);
                    g1p[rt][ks * 4 + wd] = pkmul(p, dmask(pw));
                }
    }
    // ---------- G0 = W1T * g1, then *d0 via packed mask (frags 28..35) ----------
    uint32_t g0p[2][8];
    {
        f16x8 wf[8];
        #pragma unroll
        for (int g = 0; g < 8; ++g) wf[g] = ldfragH(smem, 28 + g, lane);
        #pragma unroll
        for (int rt = 0; rt < 2; ++rt)
            #pragma unroll
            for (int t = 0; t < 4; ++t) {
                f32x4 a = {0.f, 0.f, 0.f, 0.f};
                #pragma unroll
                for (int ks = 0; ks < 2; ++ks)
                    a = MFMAH(wf[t * 2 + ks], mkfragh(&g1p[rt][ks * 4]), a, 0, 0, 0);
                acc[rt][t] = a;
            }
        #pragma unroll
        for (int rt = 0; rt < 2; ++rt)
            #pragma unroll
            for (int ks = 0; ks < 2; ++ks)
                #pragma unroll
                for (int wd = 0; wd < 4; ++wd) {
                    int tt = 2 * ks + (wd >> 1), rr = (wd & 1) * 2;
                    uint32_t pw = a0p[rt][(tt >> 1) * 4 + (tt & 1) * 2 + (rr >> 1)];
                    uint32_t p = cvtpkh(acc[rt][tt][rr], acc[rt][tt][rr + 1]);
                    g0p[rt][ks * 4 + wd] = pkmul(p, dmask(pw));
                }
    }
    // ---------- Jac = W0T * g0 (frags 36..39) ----------
    f32x4 aj[2][2];
    {
        f16x8 wf[4];
        #pragma unroll
        for (int g = 0; g < 4; ++g) wf[g] = ldfragH(smem, 36 + g, lane);
        #pragma unroll
        for (int rt = 0; rt < 2; ++rt)
            #pragma unroll
            for (int t = 0; t < 2; ++t) {
                f32x4 a = {0.f, 0.f, 0.f, 0.f};
                #pragma unroll
                for (int ks = 0; ks < 2; ++ks)
                    a = MFMAH(wf[t * 2 + ks], mkfragh(&g0p[rt][ks * 4]), a, 0, 0, 0);
                aj[rt][t] = a;
            }
    }

    // diag -> log|.| (diag d=16+z lives in tile1, reg z&3, lanes q==z>>2)
    {
        int zr = z & 3, zq = z >> 2;
        #pragma unroll
        for (int rt = 0; rt < 2; ++rt) {
            f32x4 d4 = aj[rt][1];
            float dv = (zr == 0) ? d4[0] : (zr == 1) ? d4[1] : (zr == 2) ? d4[2] : d4[3];
            float lg = __logf(fabsf(dv));
            asld += (q == zq) ? lg : 0.f;
        }
    }

    // ---------- hist_jac: direct global stores (no LDS transpose) ----------
    {
        uint32_t DW = 16 + z;
        size_t hb = 524416 + (size_t)65536 * (16 * z + (z * (z - 1)) / 2);
        #pragma unroll
        for (int rt = 0; rt < 2; ++rt) {
            int n = rowstart + rt * 16 + iN;
            float* rowp = out + hb + (size_t)n * DW;
            store4u(rowp + q * 4, aj[rt][0]);      // 16B at 4B alignment
            #pragma unroll
            for (int r = 0; r < 4; ++r)
                if (q * 4 + r < z) rowp[16 + q * 4 + r] = aj[rt][1][r];
        }
    }

    // deterministic wave-sum of log|diag|, one partial per (block, wave)
    #pragma unroll
    for (int off = 1; off < 64; off <<= 1) asld += __shfl_xor(asld, off);
    if (lane == 0) partial[(size_t)(z * 256 + blk) * 8 + wv] = asld;
}

// sld[b] = deterministic fixed-order sum of its 128 partials
__global__ void reduce_sld(const float* __restrict__ partial, float* __restrict__ sld)
{
    int b = threadIdx.x;   // 0..127
    float s = 0.f;
    #pragma unroll
    for (int z = 0; z < 8; ++z)
        #pragma unroll
        for (int k = 0; k < 2; ++k)
            #pragma unroll
            for (int w = 0; w < 8; ++w)
                s += partial[(size_t)(z * 256 + b * 2 + k) * 8 + w];
    sld[b] = s;
}

extern "C" void kernel_launch(void* const* d_in, const int* in_sizes, int n_in,
                              void* d_out, int out_size, void* d_ws, size_t ws_size,
                              hipStream_t stream) {
    const float* x    = (const float*)d_in[0];
    const float* W0   = (const float*)d_in[1];
    const float* b0   = (const float*)d_in[2];
    const float* W1   = (const float*)d_in[3];
    const float* b1   = (const float*)d_in[4];
    const float* W2   = (const float*)d_in[5];
    const float* b2   = (const float*)d_in[6];
    const float* Wout = (const float*)d_in[7];
    const float* bout = (const float*)d_in[8];

    char* ws = (char*)d_ws;
    float* out = (float*)d_out;
    float* partial = (float*)(ws + PART_BASE);

    prep_kernel<<<86, 256, 0, stream>>>(W0, b0, W1, W2, b1, b2, Wout, ws);
    flow_main<<<dim3(256, 8), 512, 0, stream>>>(x, bout, (const char*)ws, out, partial);
    reduce_sld<<<1, 128, 0, stream>>>((const float*)partial, out + (size_t)Nn * Zc);
}

// Round 16
// 45.411 us; speedup vs baseline: 6.0140x; 1.0082x over previous
//
#include <hip/hip_runtime.h>
#include <hip/hip_bf16.h>
#include <math.h>

typedef _Float16 f16x8 __attribute__((ext_vector_type(8)));
typedef _Float16 f16x2n __attribute__((ext_vector_type(2)));
typedef float f32x4 __attribute__((ext_vector_type(4)));

#define MFMAH __builtin_amdgcn_mfma_f32_16x16x32_f16

constexpr int Zc = 8, Hc = 64, Dc = 24, Tc = 512, Bc = 128, LEN = 514;
constexpr int Nn = Bc * Tc;                // 65536
constexpr size_t FRAG_Z  = 40 * 1024;      // 40 fp16 frags per z
constexpr size_t BIAS2_BASE = 8 * FRAG_Z;              // 327680 (8 z * 768B f32 bias pages)
constexpr size_t PART_BASE  = BIAS2_BASE + 8 * 768;    // 333824 (+64KB partials)

// magic row permutation: tile t, tile-row i (0..15) -> actual output index
__device__ __forceinline__ int magicRow(int t, int i) {
    return 32 * (t >> 1) + 8 * (i >> 2) + 4 * (t & 1) + (i & 3);
}
__device__ __forceinline__ uint32_t h16(float v) {   // f32 -> fp16 bits (RNE)
    union { _Float16 h; uint16_t u; } c; c.h = (_Float16)v; return (uint32_t)c.u;
}
// pack 2 f32 -> 2 fp16 in one instr (RTZ)
__device__ __forceinline__ uint32_t cvtpkh(float a, float b) {
    return __builtin_bit_cast(uint32_t, __builtin_amdgcn_cvt_pkrtz(a, b));
}
// packed fp16 multiply (v_pk_mul_f16)
__device__ __forceinline__ uint32_t pkmul(uint32_t a, uint32_t b) {
    f16x2n x = __builtin_bit_cast(f16x2n, a), y = __builtin_bit_cast(f16x2n, b);
    return __builtin_bit_cast(uint32_t, x * y);
}
// packed leaky-derivative multiplier from packed sign bits: 1.0 / 0.2 per half
__device__ __forceinline__ uint32_t dmask(uint32_t pw) {
    return 0x3C003C00u ^ (((pw & 0x80008000u) >> 15) * 0x0E66u);
}

// 16B store at 4B alignment (CDNA supports dword-aligned dwordx4 global access)
__device__ __forceinline__ void store4u(float* p, f32x4 v) {
    asm volatile("global_store_dwordx4 %0, %1, off" :: "v"(p), "v"(v) : "memory");
}

// async global -> LDS, 16B per lane (dest = uniform base + lane*16)
__device__ __forceinline__ void gload16(const char* g, char* l) {
    __builtin_amdgcn_global_load_lds(
        (const __attribute__((address_space(1))) void*)g,
        (__attribute__((address_space(3))) void*)l, 16, 0, 0);
}

__device__ __forceinline__ f16x8 ldfragH(const char* s, int f, int lane) {
    return *(const f16x8*)(s + f * 1024 + (size_t)lane * 16);  // ds_read_b128 offset:f*1024
}
__device__ __forceinline__ f16x8 mkfragh(const uint32_t* w) {
    union { uint32_t u[4]; f16x8 f; } u;
    u.u[0] = w[0]; u.u[1] = w[1]; u.u[2] = w[2]; u.u[3] = w[3]; return u.f;
}

// ---------------- prep: build fp16 weight fragments + f32 bias pages in ws ----------------
// frag map (per z, each frag = 64 lanes x 16B = 1KB):
//  0..3   W0  (t, K=32: k<24 = W0, k==24 = b0, else 0)
//  4..11  W1  (g: t=g>>1, ks=g&1)      12..19 W2
// 20..27  W2T (o=h, k=g)               28..35 W1T
// 36..39  W0T (o=d natural rows, t*2+ks)
// bias page per z: 3 sel (b1,b2,Wout) x 64 f32, idx q*16+t*4+r -> vec[magicRow(t,4q+r)]
__global__ void prep_kernel(const float* __restrict__ W0, const float* __restrict__ b0,
                            const float* __restrict__ W1, const float* __restrict__ W2,
                            const float* __restrict__ b1, const float* __restrict__ b2,
                            const float* __restrict__ Wout, char* __restrict__ ws)
{
    int idx = blockIdx.x * 256 + threadIdx.x;
    const int NFRAGL = 40 * 64 * 8;  // 20480
    if (idx < NFRAGL) {
        int z = idx / (40 * 64);
        int rem = idx % (40 * 64);
        int f = rem >> 6, l = rem & 63;
        int q = l >> 4, i = l & 15;
        uint32_t bits[8];
        #pragma unroll
        for (int e = 0; e < 8; ++e) {
            int kk = q * 8 + e;      // 0..31 within K-step
            float c = 0.f;
            if (f < 4) {                       // W0 (K=24 + bias col 24)
                int t = f;
                int o = magicRow(t, i);
                if (kk < 24) c = W0[(z * 64 + o) * 24 + kk];
                else if (kk == 24) c = b0[z * 64 + o];
            } else if (f < 12) {               // W1[g,h], o=g, k=h
                int g = f - 4;
                int t = g >> 1, ks = g & 1, k = ks * 32 + kk;
                int o = magicRow(t, i);
                c = W1[(z * 64 + o) * 64 + k];
            } else if (f < 20) {               // W2[g,h]
                int g = f - 12;
                int t = g >> 1, ks = g & 1, k = ks * 32 + kk;
                int o = magicRow(t, i);
                c = W2[(z * 64 + o) * 64 + k];
            } else if (f < 28) {               // W2T: o=h, k=g
                int g = f - 20; int t = g >> 1, ks = g & 1, k = ks * 32 + kk;
                int o = magicRow(t, i);
                c = W2[(z * 64 + k) * 64 + o];
            } else if (f < 36) {               // W1T
                int g = f - 28; int t = g >> 1, ks = g & 1, k = ks * 32 + kk;
                int o = magicRow(t, i);
                c = W1[(z * 64 + k) * 64 + o];
            } else {                           // W0T: o=d (natural), k=h
                int g = f - 36; int t = g >> 1, ks = g & 1, k = ks * 32 + kk;
                int o = t * 16 + i;
                c = (o < 24) ? W0[(z * 64 + k) * 24 + o] : 0.f;
            }
            bits[e] = h16(c);
        }
        uint4 w;
        w.x = bits[0] | (bits[1] << 16);
        w.y = bits[2] | (bits[3] << 16);
        w.z = bits[4] | (bits[5] << 16);
        w.w = bits[6] | (bits[7] << 16);
        uint4* dst = (uint4*)(ws + (size_t)z * FRAG_Z + (size_t)f * 1024);
        dst[l] = w;
    } else if (idx < NFRAGL + 1536) {
        int j2 = idx - NFRAGL;
        int z = j2 / 192, rem = j2 % 192, sel = rem >> 6, l = rem & 63;
        int q = l >> 4, t = (l >> 2) & 3, r = l & 3;
        const float* vec = (sel == 0) ? b1 + z * 64 : (sel == 1) ? b2 + z * 64 : Wout + z * 64;
        ((float*)(ws + BIAS2_BASE))[z * 192 + sel * 64 + l] = vec[magicRow(t, 4 * q + r)];
    }
}

// ---------------- main kernel: 512 threads, one z per block, single-stage 40KB LDS ----------------
__global__ __launch_bounds__(512, 4)
void flow_main(const float* __restrict__ x, const float* __restrict__ bout,
               const char* __restrict__ ws, float* __restrict__ out,
               float* __restrict__ partial)
{
    const int lane = threadIdx.x & 63;
    const int wv   = threadIdx.x >> 6;   // 0..7
    const int q    = lane >> 4;
    const int iN   = lane & 15;
    const int blk  = blockIdx.x;    // 0..255
    const int z    = blockIdx.y;    // 0..7
    const int rowstart = blk * 256 + wv * 32;

    __shared__ __align__(16) char smem[40 * 1024];   // all 40 fp16 frags

    const char* gz = ws + (size_t)z * FRAG_Z;
    const char* gbias = ws + BIAS2_BASE + (size_t)z * 768;

    // ---- stage ALL 40 frags (5 per wave), issued before input pack ----
    #pragma unroll
    for (int i = 0; i < 5; ++i) {
        int f = wv * 5 + i;
        gload16(gz + f * 1024 + lane * 16, smem + f * 1024 + lane * 16);
    }

    // ---- input frags (fp16, single term) — overlaps with staging ----
    uint32_t bh[2][4];
    #pragma unroll
    for (int rt = 0; rt < 2; ++rt) {
        int n = rowstart + rt * 16 + iN;
        int b = n >> 9, t = n & 511;
        if (q < 3) {
            const float4* xp = (const float4*)(x + (size_t)(b * LEN + t) * 8 + q * 8);
            float4 A = xp[0], B = xp[1];
            bh[rt][0] = cvtpkh(A.x, A.y);
            bh[rt][1] = cvtpkh(A.z, A.w);
            bh[rt][2] = cvtpkh(B.x, B.y);
            bh[rt][3] = cvtpkh(B.z, B.w);
        } else {   // k=24 -> 1.0 (bias slot), rest 0
            bh[rt][0] = 0x00003C00u; bh[rt][1] = bh[rt][2] = bh[rt][3] = 0;
        }
    }
    float boutz = bout[z];

    __syncthreads();   // drains vmcnt -> all frags visible to all waves

    float asld = 0.f;
    f32x4 acc[2][4];

    // ---------- L0: h0 = W0 * full (+bias via k=24) ----------
    {
        f16x8 wf[4];
        #pragma unroll
        for (int t = 0; t < 4; ++t) wf[t] = ldfragH(smem, t, lane);
        #pragma unroll
        for (int rt = 0; rt < 2; ++rt) {
            f16x8 bb = mkfragh(bh[rt]);
            #pragma unroll
            for (int t = 0; t < 4; ++t) {
                f32x4 a = {0.f, 0.f, 0.f, 0.f};
                acc[rt][t] = MFMAH(wf[t], bb, a, 0, 0, 0);
            }
        }
    }
    // leaky + pack a0 (fp16)
    uint32_t a0p[2][8];
    #pragma unroll
    for (int rt = 0; rt < 2; ++rt) {
        #pragma unroll
        for (int t = 0; t < 4; ++t)
            #pragma unroll
            for (int r = 0; r < 4; ++r) {
                float v = acc[rt][t][r];
                acc[rt][t][r] = fmaxf(v, 0.2f * v);
            }
        #pragma unroll
        for (int ks = 0; ks < 2; ++ks)
            #pragma unroll
            for (int wd = 0; wd < 4; ++wd) {
                int tt = 2 * ks + (wd >> 1), rr = (wd & 1) * 2;
                a0p[rt][ks * 4 + wd] = cvtpkh(acc[rt][tt][rr], acc[rt][tt][rr + 1]);
            }
    }

    // ---------- L1 (frags 4..11) ----------
    {
        union { float4 v; f32x4 a; } bb[4];
        const float4* bp = (const float4*)(gbias + 0 * 256 + q * 64);
        #pragma unroll
        for (int t = 0; t < 4; ++t) bb[t].v = bp[t];
        f16x8 wf[8];
        #pragma unroll
        for (int g = 0; g < 8; ++g) wf[g] = ldfragH(smem, 4 + g, lane);
        #pragma unroll
        for (int rt = 0; rt < 2; ++rt)
            #pragma unroll
            for (int t = 0; t < 4; ++t) {
                f32x4 a = bb[t].a;
                #pragma unroll
                for (int ks = 0; ks < 2; ++ks)
                    a = MFMAH(wf[t * 2 + ks], mkfragh(&a0p[rt][ks * 4]), a, 0, 0, 0);
                acc[rt][t] = a;
            }
    }
    // leaky + pack a1 (keep a0p for d0 signs)
    uint32_t a1p[2][8];
    #pragma unroll
    for (int rt = 0; rt < 2; ++rt) {
        #pragma unroll
        for (int t = 0; t < 4; ++t)
            #pragma unroll
            for (int r = 0; r < 4; ++r) {
                float v = acc[rt][t][r];
                acc[rt][t][r] = fmaxf(v, 0.2f * v);
            }
        #pragma unroll
        for (int ks = 0; ks < 2; ++ks)
            #pragma unroll
            for (int wd = 0; wd < 4; ++wd) {
                int tt = 2 * ks + (wd >> 1), rr = (wd & 1) * 2;
                a1p[rt][ks * 4 + wd] = cvtpkh(acc[rt][tt][rr], acc[rt][tt][rr + 1]);
            }
    }

    // ---------- L2 (frags 12..19; h2 stays pre-activation in acc) ----------
    {
        union { float4 v; f32x4 a; } bb[4];
        const float4* bp = (const float4*)(gbias + 1 * 256 + q * 64);
        #pragma unroll
        for (int t = 0; t < 4; ++t) bb[t].v = bp[t];
        f16x8 wf[8];
        #pragma unroll
        for (int g = 0; g < 8; ++g) wf[g] = ldfragH(smem, 12 + g, lane);
        #pragma unroll
        for (int rt = 0; rt < 2; ++rt)
            #pragma unroll
            for (int t = 0; t < 4; ++t) {
                f32x4 a = bb[t].a;
                #pragma unroll
                for (int ks = 0; ks < 2; ++ks)
                    a = MFMAH(wf[t * 2 + ks], mkfragh(&a1p[rt][ks * 4]), a, 0, 0, 0);
                acc[rt][t] = a;
            }
    }

    // ---------- out + t2 = d2*Wout ----------
    float wl[16];
    {
        const float4* wp = (const float4*)(gbias + 2 * 256 + q * 64);
        #pragma unroll
        for (int t = 0; t < 4; ++t) {
            float4 v = wp[t];
            wl[t * 4 + 0] = v.x; wl[t * 4 + 1] = v.y; wl[t * 4 + 2] = v.z; wl[t * 4 + 3] = v.w;
        }
    }
    float ov[2];
    uint32_t t2p[2][8];
    #pragma unroll
    for (int rt = 0; rt < 2; ++rt) {
        float o = 0.f;
        float t2v[16];
        #pragma unroll
        for (int t = 0; t < 4; ++t)
            #pragma unroll
            for (int r = 0; r < 4; ++r) {
                float h = acc[rt][t][r];
                float w = wl[t * 4 + r];
                float tv = (h > 0.f) ? w : 0.2f * w;
                t2v[t * 4 + r] = tv;
                o = fmaf(h, tv, o);     // h * (d2*w) == a2 * w
            }
        #pragma unroll
        for (int ks = 0; ks < 2; ++ks)
            #pragma unroll
            for (int wd = 0; wd < 4; ++wd) {
                int tt = 2 * ks + (wd >> 1), rr = (wd & 1) * 2;
                t2p[rt][ks * 4 + wd] = cvtpkh(t2v[tt * 4 + rr], t2v[tt * 4 + rr + 1]);
            }
        o += __shfl_xor(o, 16);
        o += __shfl_xor(o, 32);
        ov[rt] = o + boutz;
    }
    if (q == 0) {
        out[(size_t)(rowstart + 0 * 16 + iN) * 8 + z] = ov[0];
        out[(size_t)(rowstart + 1 * 16 + iN) * 8 + z] = ov[1];
    }

    // ---------- G1 = W2T * t2, then *d1 via packed mask (frags 20..27) ----------
    uint32_t g1p[2][8];
    {
        f16x8 wf[8];
        #pragma unroll
        for (int g = 0; g < 8; ++g) wf[g] = ldfragH(smem, 20 + g, lane);
        #pragma unroll
        for (int rt = 0; rt < 2; ++rt)
            #pragma unroll
            for (int t = 0; t < 4; ++t) {
                f32x4 a = {0.f, 0.f, 0.f, 0.f};
                #pragma unroll
                for (int ks = 0; ks < 2; ++ks)
                    a = MFMAH(wf[t * 2 + ks], mkfragh(&t2p[rt][ks * 4]), a, 0, 0, 0);
                acc[rt][t] = a;
            }
        #pragma unroll
        for (int rt = 0; rt < 2; ++rt)
            #pragma unroll
            for (int ks = 0; ks < 2; ++ks)
                #pragma unroll
                for (int wd = 0; wd < 4; ++wd) {
                    int tt = 2 * ks + (wd >> 1), rr = (wd & 1) * 2;
                    uint32_t pw = a1p[rt][(tt >> 1) * 4 + (tt & 1) * 2 + (rr >> 1)];
                    uint32_t p = cvtpkh(acc[rt][tt][rr], acc[rt][tt][rr + 1]);
                    g1p[rt][ks * 4 + wd] = pkmul(p, dmask(pw));
                }
    }
    // ---------- G0 = W1T * g1, then *d0 via packed mask (frags 28..35) ----------
    uint32_t g0p[2][8];
    {
        f16x8 wf[8];
        #pragma unroll
        for (int g = 0; g < 8; ++g) wf[g] = ldfragH(smem, 28 + g, lane);
        #pragma unroll
        for (int rt = 0; rt < 2; ++rt)
            #pragma unroll
            for (int t = 0; t < 4; ++t) {
                f32x4 a = {0.f, 0.f, 0.f, 0.f};
                #pragma unroll
                for (int ks = 0; ks < 2; ++ks)
                    a = MFMAH(wf[t * 2 + ks], mkfragh(&g1p[rt][ks * 4]), a, 0, 0, 0);
                acc[rt][t] = a;
            }
        #pragma unroll
        for (int rt = 0; rt < 2; ++rt)
            #pragma unroll
            for (int ks = 0; ks < 2; ++ks)
                #pragma unroll
                for (int wd = 0; wd < 4; ++wd) {
                    int tt = 2 * ks + (wd >> 1), rr = (wd & 1) * 2;
                    uint32_t pw = a0p[rt][(tt >> 1) * 4 + (tt & 1) * 2 + (rr >> 1)];
                    uint32_t p = cvtpkh(acc[rt][tt][rr], acc[rt][tt][rr + 1]);
                    g0p[rt][ks * 4 + wd] = pkmul(p, dmask(pw));
                }
    }
    // ---------- Jac = W0T * g0 (frags 36..39) ----------
    f32x4 aj[2][2];
    {
        f16x8 wf[4];
        #pragma unroll
        for (int g = 0; g < 4; ++g) wf[g] = ldfragH(smem, 36 + g, lane);
        #pragma unroll
        for (int rt = 0; rt < 2; ++rt)
            #pragma unroll
            for (int t = 0; t < 2; ++t) {
                f32x4 a = {0.f, 0.f, 0.f, 0.f};
                #pragma unroll
                for (int ks = 0; ks < 2; ++ks)
                    a = MFMAH(wf[t * 2 + ks], mkfragh(&g0p[rt][ks * 4]), a, 0, 0, 0);
                aj[rt][t] = a;
            }
    }

    // diag -> log|.| (diag d=16+z lives in tile1, reg z&3, lanes q==z>>2)
    {
        int zr = z & 3, zq = z >> 2;
        #pragma unroll
        for (int rt = 0; rt < 2; ++rt) {
            f32x4 d4 = aj[rt][1];
            float dv = (zr == 0) ? d4[0] : (zr == 1) ? d4[1] : (zr == 2) ? d4[2] : d4[3];
            float lg = __logf(fabsf(dv));
            asld += (q == zq) ? lg : 0.f;
        }
    }

    // ---------- hist_jac: direct global stores (no LDS transpose) ----------
    {
        uint32_t DW = 16 + z;
        size_t hb = 524416 + (size_t)65536 * (16 * z + (z * (z - 1)) / 2);
        #pragma unroll
        for (int rt = 0; rt < 2; ++rt) {
            int n = rowstart + rt * 16 + iN;
            float* rowp = out + hb + (size_t)n * DW;
            store4u(rowp + q * 4, aj[rt][0]);      // 16B at 4B alignment
            #pragma unroll
            for (int r = 0; r < 4; ++r)
                if (q * 4 + r < z) rowp[16 + q * 4 + r] = aj[rt][1][r];
        }
    }

    // deterministic wave-sum of log|diag|, one partial per (block, wave)
    #pragma unroll
    for (int off = 1; off < 64; off <<= 1) asld += __shfl_xor(asld, off);
    if (lane == 0) partial[(size_t)(z * 256 + blk) * 8 + wv] = asld;
}

// sld[b] = deterministic fixed-order sum of its 128 partials
__global__ void reduce_sld(const float* __restrict__ partial, float* __restrict__ sld)
{
    int b = threadIdx.x;   // 0..127
    float s = 0.f;
    #pragma unroll
    for (int z = 0; z < 8; ++z)
        #pragma unroll
        for (int k = 0; k < 2; ++k)
            #pragma unroll
            for (int w = 0; w < 8; ++w)
                s += partial[(size_t)(z * 256 + b * 2 + k) * 8 + w];
    sld[b] = s;
}

extern "C" void kernel_launch(void* const* d_in, const int* in_sizes, int n_in,
                              void* d_out, int out_size, void* d_ws, size_t ws_size,
                              hipStream_t stream) {
    const float* x    = (const float*)d_in[0];
    const float* W0   = (const float*)d_in[1];
    const float* b0   = (const float*)d_in[2];
    const float* W1   = (const float*)d_in[3];
    const float* b1   = (const float*)d_in[4];
    const float* W2   = (const float*)d_in[5];
    const float* b2   = (const float*)d_in[6];
    const float* Wout = (const float*)d_in[7];
    const float* bout = (const float*)d_in[8];

    char* ws = (char*)d_ws;
    float* out = (float*)d_out;
    float* partial = (float*)(ws + PART_BASE);

    prep_kernel<<<86, 256, 0, stream>>>(W0, b0, W1, W2, b1, b2, Wout, ws);
    flow_main<<<dim3(256, 8), 512, 0, stream>>>(x, bout, (const char*)ws, out, partial);
    reduce_sld<<<1, 128, 0, stream>>>((const float*)partial, out + (size_t)Nn * Zc);
}